// Round 2
// baseline (38964.124 us; speedup 1.0000x reference)
//
#include <hip/hip_runtime.h>
#include <hip/hip_cooperative_groups.h>
#include <math.h>

namespace cg = cooperative_groups;

// Problem constants
#define NB   32      // batch
#define NT   300     // encoder frames
#define NE   1024    // encoder dim
#define NH   512     // hidden
#define NA   256     // attention dim
#define NC   10      // conv channels
#define NKW  201     // conv kernel width (2K+1), K=100
#define NV   10000   // vocab
#define NEMB 512     // embedding dim
#define NAO  512     // attention output dim
#define NTD  80      // decode steps
#define SCL  2.0f
#define NBLK 256     // persistent grid blocks (1 per CU guaranteed co-resident)

__device__ __forceinline__ float sigf(float x){ return 1.f/(1.f+expf(-x)); }

// ---------------------------------------------------------------------------
// init: zbuf(dec_z)=0, dec_c=0, cvec_parts=0, prev=BOS, wbuf=w0(mask/len)
// ---------------------------------------------------------------------------
__global__ __launch_bounds__(256) void k_init(const int* __restrict__ enc_len,
    float* __restrict__ zbuf, float* __restrict__ dec_c, float* __restrict__ cp,
    float* __restrict__ wbuf, int* __restrict__ prev)
{
    int i = blockIdx.x*256 + threadIdx.x;           // 32768 threads
    if (i < NB*NH)   { zbuf[i]=0.f; dec_c[i]=0.f; }
    if (i < 2*NB*NAO)  cp[i]=0.f;
    if (i < NB*NT)   { int b=i/NT, t=i%NT; int len=enc_len[b];
                       wbuf[i] = (t<len)? 1.f/(float)len : 0.f; }
    if (i < NB)        prev[i]=1;                   // BOS
}

// ---------------------------------------------------------------------------
// Precompute pre_enc = enc_pad @ W_enc^T + b_enc.  M=9600,K=1024 exact tiles.
// ---------------------------------------------------------------------------
__global__ __launch_bounds__(256) void k_gemm_pre(const float* __restrict__ Ag,
    const float* __restrict__ Wg, const float* __restrict__ bias,
    float* __restrict__ Cg, int N)
{
    __shared__ float As[32][68];   // [kk][m]
    __shared__ float Bs[32][68];   // [kk][n]
    const int tid = threadIdx.x;
    const int m0 = blockIdx.y*64, n0 = blockIdx.x*64;
    const int r  = tid>>2, kg = (tid&3)*8;
    const int ty = tid>>4, tx = tid&15;
    float acc[4][4] = {};
    for (int k0 = 0; k0 < 1024; k0 += 32) {
        const float4 a0 = *(const float4*)(Ag + (size_t)(m0+r)*1024 + k0+kg);
        const float4 a1 = *(const float4*)(Ag + (size_t)(m0+r)*1024 + k0+kg+4);
        const float4 b0 = *(const float4*)(Wg + (size_t)(n0+r)*1024 + k0+kg);
        const float4 b1 = *(const float4*)(Wg + (size_t)(n0+r)*1024 + k0+kg+4);
        __syncthreads();
        As[kg+0][r]=a0.x; As[kg+1][r]=a0.y; As[kg+2][r]=a0.z; As[kg+3][r]=a0.w;
        As[kg+4][r]=a1.x; As[kg+5][r]=a1.y; As[kg+6][r]=a1.z; As[kg+7][r]=a1.w;
        Bs[kg+0][r]=b0.x; Bs[kg+1][r]=b0.y; Bs[kg+2][r]=b0.z; Bs[kg+3][r]=b0.w;
        Bs[kg+4][r]=b1.x; Bs[kg+5][r]=b1.y; Bs[kg+6][r]=b1.z; Bs[kg+7][r]=b1.w;
        __syncthreads();
        #pragma unroll
        for (int kk=0; kk<32; ++kk) {
            const float4 av = *(const float4*)&As[kk][ty*4];
            const float4 bv = *(const float4*)&Bs[kk][tx*4];
            const float a[4]={av.x,av.y,av.z,av.w};
            const float bb[4]={bv.x,bv.y,bv.z,bv.w};
            #pragma unroll
            for (int i=0;i<4;++i)
                #pragma unroll
                for (int j=0;j<4;++j) acc[i][j] += a[i]*bb[j];
        }
    }
    #pragma unroll
    for (int i=0;i<4;++i){
        const int m = m0 + ty*4 + i;
        #pragma unroll
        for (int j=0;j<4;++j)
            Cg[(size_t)m*N + n0 + tx*4 + j] = acc[i][j] + bias[n0+tx*4+j];
    }
}

// ===========================================================================
// Persistent cooperative kernel: whole 80-step decode loop, 7 phases/step
// separated by grid.sync().  Phase bodies identical to the proven per-step
// kernels; blockIdx remapped onto a fixed 256-block grid.
// ===========================================================================
union SMem {
    struct { float xt[32][68]; } g;                               // gates/logits
    struct { float zs[NH]; } l;                                   // lstm
    struct { float w_h[260]; float ck_s[NC*NKW]; float wt_s[NA*NC];
             float dt_s[NA]; float wg_s[NA]; float cv_s[60*NC];
             float ep_s[60][4]; } e;                              // escore
    struct { float es[NT]; float wsm[NT]; float red[256]; } c;    // ctx
    struct { float rv[256]; int ri[256]; } f;                     // fin
};

__global__ __launch_bounds__(256) void k_persist(
    const float* __restrict__ enc_pad, const float* __restrict__ embedding,
    const float* __restrict__ W_ih, const float* __restrict__ b_ih,
    const float* __restrict__ W_hh, const float* __restrict__ b_hh,
    const float* __restrict__ W_dec, const float* __restrict__ W_att,
    const float* __restrict__ conv_k, const float* __restrict__ W_g,
    const float* __restrict__ W_o, const float* __restrict__ b_o,
    const float* __restrict__ W_out, const float* __restrict__ b_out,
    const float* __restrict__ pre_enc,
    float* zbuf, float* dec_c, float* gp, float* dp, float* cp,
    float* ebuf, float* wbuf, float* ctx, float* lp, int* prev,
    float* out_logits, float* out_ws, float* out_preds, float* out_ylp)
{
    cg::grid_group grid = cg::this_grid();
    __shared__ SMem sm;
    const int bid = blockIdx.x;
    const int tid = threadIdx.x;

    for (int s = 0; s < NTD; ++s) {
        // ---------------- phase 1: gates (256 works, exact fit) ----------
        {
            const int kp = bid >> 6;                 // 0..3
            const int nb = bid & 63;                 // 0..63
            const int lane = tid&63, wv = tid>>6;
            const int bs = lane&15, nsl = lane>>4;
            const int n0 = nb*32 + wv*8 + nsl*2;
            const int sb = tid>>3, sk = (tid&7)*8;
            const int pvs = prev[sb];
            const float* wih0 = W_ih + (size_t)n0*1024;
            const float* whh0 = W_hh + (size_t)n0*512;
            float a00=0.f,a01=0.f,a10=0.f,a11=0.f;
            for (int tile=0; tile<6; ++tile) {
                const int k0 = kp*384 + tile*64;
                const int gk = k0 + sk;
                float4 v0, v1;
                if (gk < 512) {
                    const float4* p = (const float4*)(embedding + (size_t)pvs*NEMB + gk);
                    v0 = p[0]; v1 = p[1];
                } else if (gk < 1024) {
                    const float4* p0 = (const float4*)(cp + sb*NAO + (gk-512));
                    const float4* p1 = (const float4*)(cp + NB*NAO + sb*NAO + (gk-512));
                    const float4 x0=p0[0], x1=p1[0], y0=p0[1], y1=p1[1];
                    v0 = make_float4(x0.x+x1.x, x0.y+x1.y, x0.z+x1.z, x0.w+x1.w);
                    v1 = make_float4(y0.x+y1.x, y0.y+y1.y, y0.z+y1.z, y0.w+y1.w);
                } else {
                    const float4* p = (const float4*)(zbuf + sb*NH + (gk-1024));
                    v0 = p[0]; v1 = p[1];
                }
                __syncthreads();
                *(float4*)&sm.g.xt[sb][sk]   = v0;
                *(float4*)&sm.g.xt[sb][sk+4] = v1;
                __syncthreads();
                const float* w0 = (k0 < 1024) ? wih0 + k0        : whh0 + (k0-1024);
                const float* w1 = (k0 < 1024) ? wih0 + 1024 + k0 : whh0 + 512 + (k0-1024);
                #pragma unroll
                for (int c=0;c<16;++c){
                    const float4 xa = *(const float4*)&sm.g.xt[bs][c*4];
                    const float4 xb = *(const float4*)&sm.g.xt[bs+16][c*4];
                    const float4 wa = *(const float4*)(w0 + c*4);
                    const float4 wb = *(const float4*)(w1 + c*4);
                    a00 += xa.x*wa.x+xa.y*wa.y+xa.z*wa.z+xa.w*wa.w;
                    a01 += xa.x*wb.x+xa.y*wb.y+xa.z*wb.z+xa.w*wb.w;
                    a10 += xb.x*wa.x+xb.y*wa.y+xb.z*wa.z+xb.w*wa.w;
                    a11 += xb.x*wb.x+xb.y*wb.y+xb.z*wb.z+xb.w*wb.w;
                }
            }
            float* g = gp + (size_t)(kp*NB)*2048;
            g[(size_t)bs*2048 + n0]        = a00;
            g[(size_t)bs*2048 + n0+1]      = a01;
            g[(size_t)(bs+16)*2048 + n0]   = a10;
            g[(size_t)(bs+16)*2048 + n0+1] = a11;
        }
        grid.sync();

        // ---------------- phase 2: LSTM + dec_t (32 blocks) --------------
        if (bid < NB) {
            const int b = bid;
            for (int h = tid; h < NH; h += 256) {
                float g[4];
                #pragma unroll
                for (int r=0;r<4;++r){
                    float sg = b_ih[r*512+h] + b_hh[r*512+h];
                    #pragma unroll
                    for (int kp=0;kp<4;++kp) sg += gp[(size_t)(kp*NB+b)*2048 + r*512 + h];
                    g[r]=sg;
                }
                const int i = b*NH + h;
                const float c = sigf(g[1])*dec_c[i] + sigf(g[0])*tanhf(g[2]);
                dec_c[i] = c;
                const float z = sigf(g[3])*tanhf(c);
                zbuf[i] = z;
                sm.l.zs[h] = z;
            }
            __syncthreads();
            // dec_t: 32 groups of 8 lanes; group handles a = grp*8..+7
            const int grp = tid>>3, l = tid&7;
            float4 zr[16];
            #pragma unroll
            for (int q=0;q<16;++q) zr[q] = *(const float4*)&sm.l.zs[l*4 + q*32];
            #pragma unroll
            for (int j=0;j<8;++j){
                const int a = grp*8 + j;
                const float* w = W_dec + (size_t)a*NH;
                float sv = 0.f;
                #pragma unroll
                for (int q=0;q<16;++q){
                    const float4 wv = *(const float4*)(w + l*4 + q*32);
                    sv += zr[q].x*wv.x + zr[q].y*wv.y + zr[q].z*wv.z + zr[q].w*wv.w;
                }
                sv += __shfl_down(sv, 4, 8);
                sv += __shfl_down(sv, 2, 8);
                sv += __shfl_down(sv, 1, 8);
                if (l==0) dp[b*NA + a] = sv;
            }
        }
        grid.sync();

        // ---------------- phase 3: escore (160 blocks) --------------------
        if (bid < 160) {
            const int b = bid/5, t0 = (bid%5)*60;
            for (int i=tid;i<260;i+=256){ const int gt=t0-100+i;
                sm.e.w_h[i] = (gt>=0 && gt<NT)? wbuf[b*NT+gt] : 0.f; }
            for (int i=tid;i<NC*NKW;i+=256) sm.e.ck_s[i]=conv_k[i];
            for (int i=tid;i<NA*NC;i+=256)  sm.e.wt_s[i]=W_att[i];
            sm.e.dt_s[tid&255] = dp[b*NA+(tid&255)];
            sm.e.wg_s[tid&255] = W_g[tid&255];
            __syncthreads();
            for (int i=tid;i<60*NC;i+=256){
                const int tl=i/NC, ch=i%NC;
                float sv=0.f;
                const float* wp  = &sm.e.w_h[tl];
                const float* ckp = &sm.e.ck_s[ch*NKW];
                for (int k=0;k<NKW;++k) sv += wp[k]*ckp[k];
                sm.e.cv_s[i]=sv;
            }
            __syncthreads();
            const int tq = tid&3, tl = tid>>2;
            if (tl < 60) {
                float cv[NC];
                #pragma unroll
                for (int ch=0;ch<NC;++ch) cv[ch]=sm.e.cv_s[tl*NC+ch];
                const float* pe = pre_enc + (size_t)(b*NT + t0 + tl)*NA;
                float part=0.f;
                for (int i=0;i<64;++i){
                    const int aa = tq + 4*i;
                    float attc = 0.f;
                    #pragma unroll
                    for (int ch=0;ch<NC;++ch) attc += cv[ch]*sm.e.wt_s[aa*NC+ch];
                    part += tanhf(pe[aa] + sm.e.dt_s[aa] + attc) * sm.e.wg_s[aa];
                }
                sm.e.ep_s[tl][tq] = part;
            }
            __syncthreads();
            if (tid < 60)
                ebuf[b*NT + t0 + tid] = sm.e.ep_s[tid][0]+sm.e.ep_s[tid][1]
                                      + sm.e.ep_s[tid][2]+sm.e.ep_s[tid][3];
        }
        grid.sync();

        // ---------------- phase 4: softmax + ctx (128 blocks) -------------
        if (bid < 128) {
            const int b = bid>>2, d0 = (bid&3)*256;
            for (int t=tid;t<NT;t+=256) sm.c.es[t]=ebuf[b*NT+t];
            __syncthreads();
            float m=-3.4e38f;
            for (int t=tid;t<NT;t+=256) m=fmaxf(m,sm.c.es[t]);
            sm.c.red[tid]=m; __syncthreads();
            for (int r=128;r>0;r>>=1){ if(tid<r) sm.c.red[tid]=fmaxf(sm.c.red[tid],sm.c.red[tid+r]); __syncthreads(); }
            m=sm.c.red[0]; __syncthreads();
            float ss=0.f;
            for (int t=tid;t<NT;t+=256) ss+=expf(SCL*(sm.c.es[t]-m));
            sm.c.red[tid]=ss; __syncthreads();
            for (int r=128;r>0;r>>=1){ if(tid<r) sm.c.red[tid]+=sm.c.red[tid+r]; __syncthreads(); }
            const float inv = 1.f/sm.c.red[0];
            for (int t=tid;t<NT;t+=256){
                const float w = expf(SCL*(sm.c.es[t]-m))*inv;
                sm.c.wsm[t]=w;
                if ((bid&3)==0){ wbuf[b*NT+t]=w; out_ws[((size_t)b*NTD+s)*NT+t]=w; }
            }
            __syncthreads();
            const float* ep = enc_pad + (size_t)b*NT*NE + d0 + tid;
            float acc=0.f;
            #pragma unroll 4
            for (int t=0;t<NT;++t) acc += sm.c.wsm[t]*ep[(size_t)t*NE];
            ctx[b*NE + d0 + tid] = acc;
        }
        grid.sync();

        // ---------------- phase 5: cvec (32 blocks) -----------------------
        if (bid < 32) {
            const int kp = bid>>4, nb = bid&15;
            const int lane=tid&63, wv=tid>>6, bs=lane&15, nsl=lane>>4;
            const int n0 = nb*32 + wv*8 + nsl*2;
            const float* x0 = ctx + bs*NE;
            const float* x1 = ctx + (bs+16)*NE;
            const float* w0 = W_o + (size_t)n0*NE;
            const float* w1 = w0 + NE;
            float a00=0.f,a01=0.f,a10=0.f,a11=0.f;
            const int kb = kp*512;
            #pragma unroll 8
            for (int c=0;c<128;++c){
                const int k = kb + c*4;
                const float4 xa = *(const float4*)(x0+k);
                const float4 xb = *(const float4*)(x1+k);
                const float4 wa = *(const float4*)(w0+k);
                const float4 wb = *(const float4*)(w1+k);
                a00 += xa.x*wa.x+xa.y*wa.y+xa.z*wa.z+xa.w*wa.w;
                a01 += xa.x*wb.x+xa.y*wb.y+xa.z*wb.z+xa.w*wb.w;
                a10 += xb.x*wa.x+xb.y*wa.y+xb.z*wa.z+xb.w*wa.w;
                a11 += xb.x*wb.x+xb.y*wb.y+xb.z*wb.z+xb.w*wb.w;
            }
            const float bo0 = (kp==0)? b_o[n0]   : 0.f;
            const float bo1 = (kp==0)? b_o[n0+1] : 0.f;
            cp[(size_t)(kp*NB+bs)*NAO + n0]        = a00 + bo0;
            cp[(size_t)(kp*NB+bs)*NAO + n0+1]      = a01 + bo1;
            cp[(size_t)(kp*NB+bs+16)*NAO + n0]     = a10 + bo0;
            cp[(size_t)(kp*NB+bs+16)*NAO + n0+1]   = a11 + bo1;
        }
        grid.sync();

        // ---------------- phase 6: logits (626 works, looped) -------------
        for (int w = bid; w < 626; w += NBLK) {
            const int kp = w/313, nb = w%313;
            const int lane=tid&63, wv=tid>>6, bs=lane&15, nsl=lane>>4;
            const int n0 = nb*32 + wv*8 + nsl*2;
            const int rn0 = (n0   < NV)? n0   : NV-1;
            const int rn1 = (n0+1 < NV)? n0+1 : NV-1;
            const float* w0 = W_out + (size_t)rn0*1024;
            const float* w1 = W_out + (size_t)rn1*1024;
            const int sb = tid>>3, sk = (tid&7)*8;
            float a00=0.f,a01=0.f,a10=0.f,a11=0.f;
            for (int tile=0; tile<8; ++tile) {
                const int k0 = kp*512 + tile*64;
                const int gk = k0 + sk;
                float4 v0, v1;
                if (gk < 512) {
                    const float4* p = (const float4*)(zbuf + sb*NH + gk);
                    v0 = p[0]; v1 = p[1];
                } else {
                    const float4* p0 = (const float4*)(cp + sb*NAO + (gk-512));
                    const float4* p1 = (const float4*)(cp + NB*NAO + sb*NAO + (gk-512));
                    const float4 x0=p0[0], x1=p1[0], y0=p0[1], y1=p1[1];
                    v0 = make_float4(x0.x+x1.x, x0.y+x1.y, x0.z+x1.z, x0.w+x1.w);
                    v1 = make_float4(y0.x+y1.x, y0.y+y1.y, y0.z+y1.z, y0.w+y1.w);
                }
                __syncthreads();
                *(float4*)&sm.g.xt[sb][sk]   = v0;
                *(float4*)&sm.g.xt[sb][sk+4] = v1;
                __syncthreads();
                #pragma unroll
                for (int c=0;c<16;++c){
                    const float4 xa = *(const float4*)&sm.g.xt[bs][c*4];
                    const float4 xb = *(const float4*)&sm.g.xt[bs+16][c*4];
                    const float4 wa = *(const float4*)(w0 + k0 + c*4);
                    const float4 wb = *(const float4*)(w1 + k0 + c*4);
                    a00 += xa.x*wa.x+xa.y*wa.y+xa.z*wa.z+xa.w*wa.w;
                    a01 += xa.x*wb.x+xa.y*wb.y+xa.z*wb.z+xa.w*wb.w;
                    a10 += xb.x*wa.x+xb.y*wa.y+xb.z*wa.z+xb.w*wa.w;
                    a11 += xb.x*wb.x+xb.y*wb.y+xb.z*wb.z+xb.w*wb.w;
                }
            }
            if (n0 < NV){
                lp[(size_t)(kp*NB+bs)*NV + n0]    = a00;
                lp[(size_t)(kp*NB+bs+16)*NV + n0] = a10;
            }
            if (n0+1 < NV){
                lp[(size_t)(kp*NB+bs)*NV + n0+1]    = a01;
                lp[(size_t)(kp*NB+bs+16)*NV + n0+1] = a11;
            }
        }
        grid.sync();

        // ---------------- phase 7: finalize (32 blocks) -------------------
        if (bid < NB) {
            const int b = bid;
            const float* p0 = lp + (size_t)b*NV;
            const float* p1 = lp + (size_t)(NB+b)*NV;
            float* dst = out_logits + ((size_t)b*NTD + s)*NV;
            float m=-3.4e38f; int mi=NV;
            for (int v=tid; v<NV; v+=256){
                const float l = p0[v]+p1[v]+b_out[v];
                dst[v]=l;
                if (l>m){ m=l; mi=v; }
            }
            sm.f.rv[tid]=m; sm.f.ri[tid]=mi; __syncthreads();
            for (int r=128;r>0;r>>=1){
                if (tid<r){
                    if (sm.f.rv[tid+r]>sm.f.rv[tid] ||
                        (sm.f.rv[tid+r]==sm.f.rv[tid] && sm.f.ri[tid+r]<sm.f.ri[tid])){
                        sm.f.rv[tid]=sm.f.rv[tid+r]; sm.f.ri[tid]=sm.f.ri[tid+r];
                    }
                }
                __syncthreads();
            }
            m=sm.f.rv[0]; mi=sm.f.ri[0]; __syncthreads();
            float ss=0.f;
            for (int v=tid; v<NV; v+=256) ss += expf(dst[v]-m);
            sm.f.rv[tid]=ss; __syncthreads();
            for (int r=128;r>0;r>>=1){ if(tid<r) sm.f.rv[tid]+=sm.f.rv[tid+r]; __syncthreads(); }
            if (tid==0){
                prev[b]=mi;
                out_preds[b*NTD+s]=(float)mi;
                out_ylp[b*NTD+s]=-logf(sm.f.rv[0]);
            }
        }
        grid.sync();
    }
}

// ===========================================================================
// Fallback per-step kernels (used only if cooperative launch is rejected)
// ===========================================================================
__global__ __launch_bounds__(256) void k_gates(const float* __restrict__ emb,
    const int* __restrict__ prev, const float* __restrict__ cp,
    const float* __restrict__ zbuf, const float* __restrict__ W_ih,
    const float* __restrict__ W_hh, float* __restrict__ gp)
{
    __shared__ float xt[32][68];
    const int tid = threadIdx.x;
    const int kp  = blockIdx.y;
    const int lane = tid&63, wv = tid>>6;
    const int bs = lane&15, nsl = lane>>4;
    const int n0 = blockIdx.x*32 + wv*8 + nsl*2;
    const int sb = tid>>3, sk = (tid&7)*8;
    const int pvs = prev[sb];
    const float* wih0 = W_ih + (size_t)n0*1024;
    const float* whh0 = W_hh + (size_t)n0*512;
    float a00=0.f,a01=0.f,a10=0.f,a11=0.f;
    for (int tile=0; tile<6; ++tile) {
        const int k0 = kp*384 + tile*64;
        const int gk = k0 + sk;
        float4 v0, v1;
        if (gk < 512) {
            const float4* p = (const float4*)(emb + (size_t)pvs*NEMB + gk);
            v0 = p[0]; v1 = p[1];
        } else if (gk < 1024) {
            const float4* p0 = (const float4*)(cp + sb*NAO + (gk-512));
            const float4* p1 = (const float4*)(cp + NB*NAO + sb*NAO + (gk-512));
            const float4 x0=p0[0], x1=p1[0], y0=p0[1], y1=p1[1];
            v0 = make_float4(x0.x+x1.x, x0.y+x1.y, x0.z+x1.z, x0.w+x1.w);
            v1 = make_float4(y0.x+y1.x, y0.y+y1.y, y0.z+y1.z, y0.w+y1.w);
        } else {
            const float4* p = (const float4*)(zbuf + sb*NH + (gk-1024));
            v0 = p[0]; v1 = p[1];
        }
        __syncthreads();
        *(float4*)&xt[sb][sk]   = v0;
        *(float4*)&xt[sb][sk+4] = v1;
        __syncthreads();
        const float* w0 = (k0 < 1024) ? wih0 + k0        : whh0 + (k0-1024);
        const float* w1 = (k0 < 1024) ? wih0 + 1024 + k0 : whh0 + 512 + (k0-1024);
        #pragma unroll
        for (int c=0;c<16;++c){
            const float4 xa = *(const float4*)&xt[bs][c*4];
            const float4 xb = *(const float4*)&xt[bs+16][c*4];
            const float4 wa = *(const float4*)(w0 + c*4);
            const float4 wb = *(const float4*)(w1 + c*4);
            a00 += xa.x*wa.x+xa.y*wa.y+xa.z*wa.z+xa.w*wa.w;
            a01 += xa.x*wb.x+xa.y*wb.y+xa.z*wb.z+xa.w*wb.w;
            a10 += xb.x*wa.x+xb.y*wa.y+xb.z*wa.z+xb.w*wa.w;
            a11 += xb.x*wb.x+xb.y*wb.y+xb.z*wb.z+xb.w*wb.w;
        }
    }
    float* g = gp + (size_t)(kp*NB)*2048;
    g[(size_t)bs*2048 + n0]        = a00;
    g[(size_t)bs*2048 + n0+1]      = a01;
    g[(size_t)(bs+16)*2048 + n0]   = a10;
    g[(size_t)(bs+16)*2048 + n0+1] = a11;
}

__global__ __launch_bounds__(512) void k_lstm_dect(const float* __restrict__ gp,
    const float* __restrict__ b_ih, const float* __restrict__ b_hh,
    float* __restrict__ dec_c, float* __restrict__ zbuf,
    const float* __restrict__ W_dec, float* __restrict__ dp)
{
    __shared__ float zs[NH];
    const int b = blockIdx.x, tid = threadIdx.x;
    const int h = tid;
    float g[4];
    #pragma unroll
    for (int r=0;r<4;++r){
        float s = b_ih[r*512+h] + b_hh[r*512+h];
        #pragma unroll
        for (int kp=0;kp<4;++kp) s += gp[(size_t)(kp*NB+b)*2048 + r*512 + h];
        g[r]=s;
    }
    const int i = b*NH + h;
    const float c = sigf(g[1])*dec_c[i] + sigf(g[0])*tanhf(g[2]);
    dec_c[i] = c;
    const float z = sigf(g[3])*tanhf(c);
    zbuf[i] = z;
    zs[h]   = z;
    __syncthreads();
    const int grp = tid>>4, l = tid&15;
    float4 zr[8];
    #pragma unroll
    for (int q=0;q<8;++q) zr[q] = *(const float4*)&zs[l*4 + q*64];
    #pragma unroll
    for (int j=0;j<8;++j){
        const int a = grp*8 + j;
        const float* w = W_dec + (size_t)a*NH;
        float s = 0.f;
        #pragma unroll
        for (int q=0;q<8;++q){
            const float4 wv = *(const float4*)(w + l*4 + q*64);
            s += zr[q].x*wv.x + zr[q].y*wv.y + zr[q].z*wv.z + zr[q].w*wv.w;
        }
        s += __shfl_down(s, 8, 16);
        s += __shfl_down(s, 4, 16);
        s += __shfl_down(s, 2, 16);
        s += __shfl_down(s, 1, 16);
        if (l==0) dp[b*NA + a] = s;
    }
}

__global__ __launch_bounds__(256) void k_escore(const float* __restrict__ pre_enc,
    const float* __restrict__ wprev, const float* __restrict__ ck,
    const float* __restrict__ W_att, const float* __restrict__ dp,
    const float* __restrict__ W_g, float* __restrict__ ebuf)
{
    __shared__ float w_h[260];
    __shared__ float ck_s[NC*NKW];
    __shared__ float wt_s[NA*NC];
    __shared__ float dt_s[NA];
    __shared__ float wg_s[NA];
    __shared__ float cv_s[60*NC];
    __shared__ float ep_s[60][4];
    const int tid = threadIdx.x;
    const int b = blockIdx.y, t0 = blockIdx.x*60;
    for (int i=tid;i<260;i+=256){ const int gt=t0-100+i;
        w_h[i] = (gt>=0 && gt<NT)? wprev[b*NT+gt] : 0.f; }
    for (int i=tid;i<NC*NKW;i+=256) ck_s[i]=ck[i];
    for (int i=tid;i<NA*NC;i+=256)  wt_s[i]=W_att[i];
    dt_s[tid&255] = dp[b*NA+(tid&255)];
    wg_s[tid&255] = W_g[tid&255];
    __syncthreads();
    for (int i=tid;i<60*NC;i+=256){
        const int tl=i/NC, ch=i%NC;
        float s=0.f;
        const float* wp  = &w_h[tl];
        const float* ckp = &ck_s[ch*NKW];
        for (int k=0;k<NKW;++k) s += wp[k]*ckp[k];
        cv_s[i]=s;
    }
    __syncthreads();
    const int tq = tid&3, tl = tid>>2;
    if (tl < 60) {
        float cv[NC];
        #pragma unroll
        for (int ch=0;ch<NC;++ch) cv[ch]=cv_s[tl*NC+ch];
        const float* pe = pre_enc + (size_t)(b*NT + t0 + tl)*NA;
        float part=0.f;
        for (int i=0;i<64;++i){
            const int aa = tq + 4*i;
            float attc = 0.f;
            #pragma unroll
            for (int ch=0;ch<NC;++ch) attc += cv[ch]*wt_s[aa*NC+ch];
            part += tanhf(pe[aa] + dt_s[aa] + attc) * wg_s[aa];
        }
        ep_s[tl][tq] = part;
    }
    __syncthreads();
    if (tid < 60)
        ebuf[b*NT + t0 + tid] = ep_s[tid][0]+ep_s[tid][1]+ep_s[tid][2]+ep_s[tid][3];
}

__global__ __launch_bounds__(256) void k_ctx(const float* __restrict__ ebuf,
    const float* __restrict__ enc_pad, float* __restrict__ ctx,
    float* __restrict__ wbuf, float* __restrict__ out_ws, int step)
{
    __shared__ float es[NT], wsm[NT], red[256];
    const int tid=threadIdx.x, b=blockIdx.y, d0=blockIdx.x*256;
    for (int t=tid;t<NT;t+=256) es[t]=ebuf[b*NT+t];
    __syncthreads();
    float m=-3.4e38f;
    for (int t=tid;t<NT;t+=256) m=fmaxf(m,es[t]);
    red[tid]=m; __syncthreads();
    for (int s=128;s>0;s>>=1){ if(tid<s) red[tid]=fmaxf(red[tid],red[tid+s]); __syncthreads(); }
    m=red[0]; __syncthreads();
    float ss=0.f;
    for (int t=tid;t<NT;t+=256) ss+=expf(SCL*(es[t]-m));
    red[tid]=ss; __syncthreads();
    for (int s=128;s>0;s>>=1){ if(tid<s) red[tid]+=red[tid+s]; __syncthreads(); }
    const float inv = 1.f/red[0];
    for (int t=tid;t<NT;t+=256){
        const float w = expf(SCL*(es[t]-m))*inv;
        wsm[t]=w;
        if (blockIdx.x==0){ wbuf[b*NT+t]=w; out_ws[((size_t)b*NTD+step)*NT+t]=w; }
    }
    __syncthreads();
    const float* ep = enc_pad + (size_t)b*NT*NE + d0 + tid;
    float acc=0.f;
    #pragma unroll 4
    for (int t=0;t<NT;++t) acc += wsm[t]*ep[(size_t)t*NE];
    ctx[b*NE + d0 + tid] = acc;
}

__global__ __launch_bounds__(256) void k_cvec(const float* __restrict__ ctx,
    const float* __restrict__ W_o, const float* __restrict__ b_o,
    float* __restrict__ cp)
{
    const int tid=threadIdx.x, kp=blockIdx.y;
    const int lane=tid&63, wv=tid>>6, bs=lane&15, nsl=lane>>4;
    const int n0 = blockIdx.x*32 + wv*8 + nsl*2;
    const float* x0 = ctx + bs*NE;
    const float* x1 = ctx + (bs+16)*NE;
    const float* w0 = W_o + (size_t)n0*NE;
    const float* w1 = w0 + NE;
    float a00=0.f,a01=0.f,a10=0.f,a11=0.f;
    const int kb = kp*512;
    #pragma unroll 8
    for (int c=0;c<128;++c){
        const int k = kb + c*4;
        const float4 xa = *(const float4*)(x0+k);
        const float4 xb = *(const float4*)(x1+k);
        const float4 wa = *(const float4*)(w0+k);
        const float4 wb = *(const float4*)(w1+k);
        a00 += xa.x*wa.x+xa.y*wa.y+xa.z*wa.z+xa.w*wa.w;
        a01 += xa.x*wb.x+xa.y*wb.y+xa.z*wb.z+xa.w*wb.w;
        a10 += xb.x*wa.x+xb.y*wa.y+xb.z*wa.z+xb.w*wa.w;
        a11 += xb.x*wb.x+xb.y*wb.y+xb.z*wb.z+xb.w*wb.w;
    }
    const float bo0 = (kp==0)? b_o[n0]   : 0.f;
    const float bo1 = (kp==0)? b_o[n0+1] : 0.f;
    cp[(size_t)(kp*NB+bs)*NAO + n0]        = a00 + bo0;
    cp[(size_t)(kp*NB+bs)*NAO + n0+1]      = a01 + bo1;
    cp[(size_t)(kp*NB+bs+16)*NAO + n0]     = a10 + bo0;
    cp[(size_t)(kp*NB+bs+16)*NAO + n0+1]   = a11 + bo1;
}

__global__ __launch_bounds__(256) void k_logits(const float* __restrict__ zbuf,
    const float* __restrict__ cp, const float* __restrict__ W_out,
    float* __restrict__ lp)
{
    __shared__ float xt[32][68];
    const int tid=threadIdx.x, kp=blockIdx.y;
    const int lane=tid&63, wv=tid>>6, bs=lane&15, nsl=lane>>4;
    const int n0 = blockIdx.x*32 + wv*8 + nsl*2;
    const int rn0 = (n0   < NV)? n0   : NV-1;
    const int rn1 = (n0+1 < NV)? n0+1 : NV-1;
    const float* w0 = W_out + (size_t)rn0*1024;
    const float* w1 = W_out + (size_t)rn1*1024;
    const int sb = tid>>3, sk = (tid&7)*8;
    float a00=0.f,a01=0.f,a10=0.f,a11=0.f;
    for (int tile=0; tile<8; ++tile) {
        const int k0 = kp*512 + tile*64;
        const int gk = k0 + sk;
        float4 v0, v1;
        if (gk < 512) {
            const float4* p = (const float4*)(zbuf + sb*NH + gk);
            v0 = p[0]; v1 = p[1];
        } else {
            const float4* p0 = (const float4*)(cp + sb*NAO + (gk-512));
            const float4* p1 = (const float4*)(cp + NB*NAO + sb*NAO + (gk-512));
            const float4 x0=p0[0], x1=p1[0], y0=p0[1], y1=p1[1];
            v0 = make_float4(x0.x+x1.x, x0.y+x1.y, x0.z+x1.z, x0.w+x1.w);
            v1 = make_float4(y0.x+y1.x, y0.y+y1.y, y0.z+y1.z, y0.w+y1.w);
        }
        __syncthreads();
        *(float4*)&xt[sb][sk]   = v0;
        *(float4*)&xt[sb][sk+4] = v1;
        __syncthreads();
        #pragma unroll
        for (int c=0;c<16;++c){
            const float4 xa = *(const float4*)&xt[bs][c*4];
            const float4 xb = *(const float4*)&xt[bs+16][c*4];
            const float4 wa = *(const float4*)(w0 + k0 + c*4);
            const float4 wb = *(const float4*)(w1 + k0 + c*4);
            a00 += xa.x*wa.x+xa.y*wa.y+xa.z*wa.z+xa.w*wa.w;
            a01 += xa.x*wb.x+xa.y*wb.y+xa.z*wb.z+xa.w*wb.w;
            a10 += xb.x*wa.x+xb.y*wa.y+xb.z*wa.z+xb.w*wa.w;
            a11 += xb.x*wb.x+xb.y*wb.y+xb.z*wb.z+xb.w*wb.w;
        }
    }
    if (n0 < NV){
        lp[(size_t)(kp*NB+bs)*NV + n0]    = a00;
        lp[(size_t)(kp*NB+bs+16)*NV + n0] = a10;
    }
    if (n0+1 < NV){
        lp[(size_t)(kp*NB+bs)*NV + n0+1]    = a01;
        lp[(size_t)(kp*NB+bs+16)*NV + n0+1] = a11;
    }
}

__global__ __launch_bounds__(256) void k_fin(const float* __restrict__ lp,
    const float* __restrict__ b_out, int step, float* __restrict__ out_logits,
    int* __restrict__ prev, float* __restrict__ out_preds, float* __restrict__ out_ylp)
{
    __shared__ float rv[256];
    __shared__ int   ri[256];
    const int b=blockIdx.x, tid=threadIdx.x;
    const float* p0 = lp + (size_t)b*NV;
    const float* p1 = lp + (size_t)(NB+b)*NV;
    float* dst = out_logits + ((size_t)b*NTD + step)*NV;
    float m=-3.4e38f; int mi=NV;
    for (int v=tid; v<NV; v+=256){
        const float l = p0[v]+p1[v]+b_out[v];
        dst[v]=l;
        if (l>m){ m=l; mi=v; }
    }
    rv[tid]=m; ri[tid]=mi; __syncthreads();
    for (int s=128;s>0;s>>=1){
        if (tid<s){
            if (rv[tid+s]>rv[tid] || (rv[tid+s]==rv[tid] && ri[tid+s]<ri[tid])){
                rv[tid]=rv[tid+s]; ri[tid]=ri[tid+s];
            }
        }
        __syncthreads();
    }
    m=rv[0]; mi=ri[0]; __syncthreads();
    float ss=0.f;
    for (int v=tid; v<NV; v+=256) ss += expf(dst[v]-m);
    rv[tid]=ss; __syncthreads();
    for (int s=128;s>0;s>>=1){ if(tid<s) rv[tid]+=rv[tid+s]; __syncthreads(); }
    if (tid==0){
        prev[b]=mi;
        out_preds[b*NTD+step]=(float)mi;
        out_ylp[b*NTD+step]=-logf(rv[0]);
    }
}

// ---------------------------------------------------------------------------
extern "C" void kernel_launch(void* const* d_in, const int* in_sizes, int n_in,
                              void* d_out, int out_size, void* d_ws, size_t ws_size,
                              hipStream_t stream)
{
    const float* enc_pad   = (const float*)d_in[0];
    const int*   enc_len   = (const int*)d_in[1];
    const float* embedding = (const float*)d_in[2];
    const float* W_ih      = (const float*)d_in[3];
    const float* b_ih      = (const float*)d_in[4];
    const float* W_hh      = (const float*)d_in[5];
    const float* b_hh      = (const float*)d_in[6];
    const float* W_enc     = (const float*)d_in[7];
    const float* b_enc     = (const float*)d_in[8];
    const float* W_dec     = (const float*)d_in[9];
    const float* W_att     = (const float*)d_in[10];
    const float* conv_k    = (const float*)d_in[11];
    const float* W_g       = (const float*)d_in[12];
    const float* W_o       = (const float*)d_in[13];
    const float* b_o       = (const float*)d_in[14];
    const float* W_out     = (const float*)d_in[15];
    const float* b_out     = (const float*)d_in[16];

    float* out_logits = (float*)d_out;                        // [B,TD,V]
    float* out_ylp    = out_logits + (size_t)NB*NTD*NV;       // [B,TD]
    float* out_preds  = out_ylp + NB*NTD;                     // [B,TD]
    float* out_ws     = out_preds + NB*NTD;                   // [B,TD,T]

    float* f = (float*)d_ws;
    float* pre_enc = f;                                   // 9600*256
    float* zbuf    = pre_enc + (size_t)NB*NT*NA;          // 32*512  (dec_z)
    float* dec_c   = zbuf + NB*NH;                        // 32*512
    float* gp      = dec_c + NB*NH;                       // 4*32*2048
    float* dp      = gp + 4*NB*2048;                      // 32*256 (region sized 2x)
    float* cp      = dp + 2*NB*NA;                        // 2*32*512
    float* ebuf    = cp + 2*NB*NAO;                       // 32*300
    float* wbuf    = ebuf + NB*NT;                        // 32*300
    float* ctx     = wbuf + NB*NT;                        // 32*1024
    float* lp      = ctx + NB*NE;                         // 2*32*10000
    int*   prev    = (int*)(lp + (size_t)2*NB*NV);        // 32

    k_init<<<128, 256, 0, stream>>>(enc_len, zbuf, dec_c, cp, wbuf, prev);
    k_gemm_pre<<<dim3(NA/64, NB*NT/64), 256, 0, stream>>>(enc_pad, W_enc, b_enc, pre_enc, NA);

    void* args[] = {
        (void*)&enc_pad, (void*)&embedding, (void*)&W_ih, (void*)&b_ih,
        (void*)&W_hh, (void*)&b_hh, (void*)&W_dec, (void*)&W_att,
        (void*)&conv_k, (void*)&W_g, (void*)&W_o, (void*)&b_o,
        (void*)&W_out, (void*)&b_out, (void*)&pre_enc,
        (void*)&zbuf, (void*)&dec_c, (void*)&gp, (void*)&dp, (void*)&cp,
        (void*)&ebuf, (void*)&wbuf, (void*)&ctx, (void*)&lp, (void*)&prev,
        (void*)&out_logits, (void*)&out_ws, (void*)&out_preds, (void*)&out_ylp };
    hipError_t cerr = hipLaunchCooperativeKernel(k_persist, dim3(NBLK), dim3(256),
                                                 args, 0u, stream);
    if (cerr != hipSuccess) {
        // Fallback: proven per-step dispatch chain
        for (int s = 0; s < NTD; ++s) {
            k_gates    <<<dim3(64,4),  256, 0, stream>>>(embedding, prev, cp, zbuf, W_ih, W_hh, gp);
            k_lstm_dect<<<NB,          512, 0, stream>>>(gp, b_ih, b_hh, dec_c, zbuf, W_dec, dp);
            k_escore   <<<dim3(5,32),  256, 0, stream>>>(pre_enc, wbuf, conv_k, W_att, dp, W_g, ebuf);
            k_ctx      <<<dim3(4,32),  256, 0, stream>>>(ebuf, enc_pad, ctx, wbuf, out_ws, s);
            k_cvec     <<<dim3(16,2),  256, 0, stream>>>(ctx, W_o, b_o, cp);
            k_logits   <<<dim3(313,2), 256, 0, stream>>>(zbuf, cp, W_out, lp);
            k_fin      <<<32,          256, 0, stream>>>(lp, b_out, s, out_logits, prev, out_preds, out_ylp);
        }
    }
}

// Round 3
// 29963.232 us; speedup vs baseline: 1.3004x; 1.3004x over previous
//
#include <hip/hip_runtime.h>
#include <math.h>

// Problem constants
#define NB   32      // batch
#define NT   300     // encoder frames
#define NE   1024    // encoder dim
#define NH   512     // hidden
#define NA   256     // attention dim
#define NC   10      // conv channels
#define NKW  201     // conv kernel width (2K+1), K=100
#define NV   10000   // vocab
#define NEMB 512     // embedding dim
#define NAO  512     // attention output dim
#define NTD  80      // decode steps
#define SCL  2.0f

__device__ __forceinline__ float sigf(float x){ return 1.f/(1.f+expf(-x)); }

// ---------------------------------------------------------------------------
// init: zA(dec_z)=0, dec_c=0, cv=0, prev=BOS, wA=w0(mask/len)
// ---------------------------------------------------------------------------
__global__ __launch_bounds__(256) void k_init(const int* __restrict__ enc_len,
    float* __restrict__ zA, float* __restrict__ dec_c, float* __restrict__ cv,
    float* __restrict__ wA, int* __restrict__ prev)
{
    int i = blockIdx.x*256 + threadIdx.x;           // 32768 threads
    if (i < NB*NH)   { zA[i]=0.f; dec_c[i]=0.f; }
    if (i < NB*NAO)    cv[i]=0.f;
    if (i < NB*NT)   { int b=i/NT, t=i%NT; int len=enc_len[b];
                       wA[i] = (t<len)? 1.f/(float)len : 0.f; }
    if (i < NB)        prev[i]=1;                   // BOS
}

// ---------------------------------------------------------------------------
// Precompute pre_enc = enc_pad @ W_enc^T + b_enc.  M=9600,K=1024 exact tiles.
// ---------------------------------------------------------------------------
__global__ __launch_bounds__(256) void k_gemm_pre(const float* __restrict__ Ag,
    const float* __restrict__ Wg, const float* __restrict__ bias,
    float* __restrict__ Cg, int N)
{
    __shared__ float As[32][68];   // [kk][m]
    __shared__ float Bs[32][68];   // [kk][n]
    const int tid = threadIdx.x;
    const int m0 = blockIdx.y*64, n0 = blockIdx.x*64;
    const int r  = tid>>2, kg = (tid&3)*8;
    const int ty = tid>>4, tx = tid&15;
    float acc[4][4] = {};
    for (int k0 = 0; k0 < 1024; k0 += 32) {
        const float4 a0 = *(const float4*)(Ag + (size_t)(m0+r)*1024 + k0+kg);
        const float4 a1 = *(const float4*)(Ag + (size_t)(m0+r)*1024 + k0+kg+4);
        const float4 b0 = *(const float4*)(Wg + (size_t)(n0+r)*1024 + k0+kg);
        const float4 b1 = *(const float4*)(Wg + (size_t)(n0+r)*1024 + k0+kg+4);
        __syncthreads();
        As[kg+0][r]=a0.x; As[kg+1][r]=a0.y; As[kg+2][r]=a0.z; As[kg+3][r]=a0.w;
        As[kg+4][r]=a1.x; As[kg+5][r]=a1.y; As[kg+6][r]=a1.z; As[kg+7][r]=a1.w;
        Bs[kg+0][r]=b0.x; Bs[kg+1][r]=b0.y; Bs[kg+2][r]=b0.z; Bs[kg+3][r]=b0.w;
        Bs[kg+4][r]=b1.x; Bs[kg+5][r]=b1.y; Bs[kg+6][r]=b1.z; Bs[kg+7][r]=b1.w;
        __syncthreads();
        #pragma unroll
        for (int kk=0; kk<32; ++kk) {
            const float4 av = *(const float4*)&As[kk][ty*4];
            const float4 bv = *(const float4*)&Bs[kk][tx*4];
            const float a[4]={av.x,av.y,av.z,av.w};
            const float bb[4]={bv.x,bv.y,bv.z,bv.w};
            #pragma unroll
            for (int i=0;i<4;++i)
                #pragma unroll
                for (int j=0;j<4;++j) acc[i][j] += a[i]*bb[j];
        }
    }
    #pragma unroll
    for (int i=0;i<4;++i){
        const int m = m0 + ty*4 + i;
        #pragma unroll
        for (int j=0;j<4;++j)
            Cg[(size_t)m*N + n0 + tx*4 + j] = acc[i][j] + bias[n0+tx*4+j];
    }
}

// ---------------------------------------------------------------------------
// FUSED gates + LSTM.  64 blocks, 256 thr.  Block x owns h in [x*8, x*8+8):
// its 32 weight rows are {r*512 + h : r in 0..3} -> full gate sums in-block,
// then the LSTM update for those 8 h x 32 b runs after one barrier.
// x = [emb[prev] (512) | cv (512) | z_in (512)], full K=1536.
// z double-buffered: reads zin (all blocks), writes zout (owner rows only).
// ---------------------------------------------------------------------------
__global__ __launch_bounds__(256) void k_gatelstm(
    const float* __restrict__ emb, const int* __restrict__ prev,
    const float* __restrict__ cv, const float* __restrict__ zin,
    const float* __restrict__ W_ih, const float* __restrict__ b_ih,
    const float* __restrict__ W_hh, const float* __restrict__ b_hh,
    float* __restrict__ dec_c, float* __restrict__ zout)
{
    __shared__ float xt[32][68];
    __shared__ float gs[32][33];
    const int tid = threadIdx.x;
    const int h0 = blockIdx.x*8;
    const int lane = tid&63, wv = tid>>6;           // wv = gate index r
    const int bs = lane&15, nsl = lane>>4;
    const int rn0 = wv*8 + nsl*2;                   // local row in gs
    const int n0  = wv*512 + h0 + nsl*2;            // global gate row
    const int sb = tid>>3, sk = (tid&7)*8;
    const int pvs = prev[sb];
    const float* wih0 = W_ih + (size_t)n0*1024;
    const float* whh0 = W_hh + (size_t)n0*512;
    float a00=0.f,a01=0.f,a10=0.f,a11=0.f;
    for (int tile=0; tile<24; ++tile) {
        const int k0 = tile*64;
        const int gk = k0 + sk;
        float4 v0, v1;
        if (gk < 512) {
            const float4* p = (const float4*)(emb + (size_t)pvs*NEMB + gk);
            v0 = p[0]; v1 = p[1];
        } else if (gk < 1024) {
            const float4* p = (const float4*)(cv + sb*NAO + (gk-512));
            v0 = p[0]; v1 = p[1];
        } else {
            const float4* p = (const float4*)(zin + sb*NH + (gk-1024));
            v0 = p[0]; v1 = p[1];
        }
        __syncthreads();
        *(float4*)&xt[sb][sk]   = v0;
        *(float4*)&xt[sb][sk+4] = v1;
        __syncthreads();
        const float* w0 = (k0 < 1024) ? wih0 + k0        : whh0 + (k0-1024);
        const float* w1 = (k0 < 1024) ? wih0 + 1024 + k0 : whh0 + 512 + (k0-1024);
        #pragma unroll
        for (int c=0;c<16;++c){
            const float4 xa = *(const float4*)&xt[bs][c*4];
            const float4 xb = *(const float4*)&xt[bs+16][c*4];
            const float4 wa = *(const float4*)(w0 + c*4);
            const float4 wb = *(const float4*)(w1 + c*4);
            a00 += xa.x*wa.x+xa.y*wa.y+xa.z*wa.z+xa.w*wa.w;
            a01 += xa.x*wb.x+xa.y*wb.y+xa.z*wb.z+xa.w*wb.w;
            a10 += xb.x*wa.x+xb.y*wa.y+xb.z*wa.z+xb.w*wa.w;
            a11 += xb.x*wb.x+xb.y*wb.y+xb.z*wb.z+xb.w*wb.w;
        }
    }
    const float bz0 = b_ih[n0]   + b_hh[n0];
    const float bz1 = b_ih[n0+1] + b_hh[n0+1];
    gs[bs][rn0]      = a00 + bz0;
    gs[bs][rn0+1]    = a01 + bz1;
    gs[bs+16][rn0]   = a10 + bz0;
    gs[bs+16][rn0+1] = a11 + bz1;
    __syncthreads();
    // LSTM update: thread -> (b, j); gs rows: [0..8)=i, [8..16)=f, [16..24)=g, [24..32)=o
    const int b = tid&31, j = tid>>5;
    const float gi = gs[b][j],    gf = gs[b][8+j];
    const float gg = gs[b][16+j], go = gs[b][24+j];
    const int idx = b*NH + h0 + j;
    const float c = sigf(gf)*dec_c[idx] + sigf(gi)*tanhf(gg);
    dec_c[idx] = c;
    zout[idx]  = sigf(go)*tanhf(c);
}

// ---------------------------------------------------------------------------
// FUSED dec_t + conv + escore + softmax + ctx.  128 blocks = 4 per batch.
// The 4 blocks of a batch redundantly compute dec_t/conv/escore/softmax
// (runs in parallel on different CUs -> no wall-time cost), then each takes
// one 256-wide d-quarter of ctx.  q==0 writes wbuf(next) + out_ws.
// wbuf double-buffered (win read, wout written) to avoid same-kernel races.
// ---------------------------------------------------------------------------
__global__ __launch_bounds__(256) void k_att(
    const float* __restrict__ pre_enc, const float* __restrict__ win,
    const float* __restrict__ ck, const float* __restrict__ W_att,
    const float* __restrict__ W_dec, const float* __restrict__ W_g,
    const float* __restrict__ zbuf, const float* __restrict__ enc_pad,
    float* __restrict__ ctx, float* __restrict__ wout,
    float* __restrict__ out_ws, int step)
{
    __shared__ float zs[NH];           // 512
    __shared__ float w_h[500];
    __shared__ float ck_s[NC*NKW];     // 2010
    __shared__ float wt_s[NA*NC];      // 2560
    __shared__ float dt_s[NA];
    __shared__ float wg_s[NA];
    __shared__ float cv_s[NT*NC];      // 3000
    __shared__ float esr[NT];
    __shared__ float wsm[NT];
    __shared__ float red[256];
    __shared__ float ep_s[64][4];
    const int tid = threadIdx.x;
    const int b = blockIdx.x>>2, q = blockIdx.x&3;
    // ---- loads
    for (int i=tid;i<NH;i+=256) zs[i] = zbuf[b*NH+i];
    for (int i=tid;i<500;i+=256){ const int gt=i-100;
        w_h[i] = (gt>=0 && gt<NT)? win[b*NT+gt] : 0.f; }
    for (int i=tid;i<NC*NKW;i+=256) ck_s[i]=ck[i];
    for (int i=tid;i<NA*NC;i+=256)  wt_s[i]=W_att[i];
    wg_s[tid] = W_g[tid];
    __syncthreads();
    // ---- dec_t: 32 groups of 8 lanes; group handles a = grp*8..+7
    {
        const int grp = tid>>3, l = tid&7;
        float4 zr[16];
        #pragma unroll
        for (int qq=0;qq<16;++qq) zr[qq] = *(const float4*)&zs[l*4 + qq*32];
        #pragma unroll
        for (int j=0;j<8;++j){
            const int a = grp*8 + j;
            const float* w = W_dec + (size_t)a*NH;
            float sv = 0.f;
            #pragma unroll
            for (int qq=0;qq<16;++qq){
                const float4 wv4 = *(const float4*)(w + l*4 + qq*32);
                sv += zr[qq].x*wv4.x + zr[qq].y*wv4.y + zr[qq].z*wv4.z + zr[qq].w*wv4.w;
            }
            sv += __shfl_down(sv, 4, 8);
            sv += __shfl_down(sv, 2, 8);
            sv += __shfl_down(sv, 1, 8);
            if (l==0) dt_s[a] = sv;
        }
    }
    __syncthreads();
    // ---- conv: cv[t][ch] = sum_k w_h[t+k]*ck[ch][k]
    for (int i=tid;i<NT*NC;i+=256){
        const int tl=i/NC, ch=i%NC;
        float s=0.f;
        const float* wp  = &w_h[tl];
        const float* ckp = &ck_s[ch*NKW];
        for (int k=0;k<NKW;++k) s += wp[k]*ckp[k];
        cv_s[i]=s;
    }
    __syncthreads();
    // ---- escore: 5 passes of 64 t; 4 lanes split the a-dim
    const int tq = tid&3, tl = tid>>2;
    for (int p=0;p<5;++p){
        const int t = p*64 + tl;
        float part = 0.f;
        if (t < NT){
            float cvr[NC];
            #pragma unroll
            for (int ch=0;ch<NC;++ch) cvr[ch]=cv_s[t*NC+ch];
            const float* pe = pre_enc + (size_t)(b*NT + t)*NA;
            for (int i=0;i<64;++i){
                const int aa = tq + 4*i;
                float attc = 0.f;
                #pragma unroll
                for (int ch=0;ch<NC;++ch) attc += cvr[ch]*wt_s[aa*NC+ch];
                part += tanhf(pe[aa] + dt_s[aa] + attc) * wg_s[aa];
            }
        }
        ep_s[tl][tq] = part;
        __syncthreads();
        if (tid < 64){ const int t2 = p*64 + tid;
            if (t2 < NT) esr[t2] = ep_s[tid][0]+ep_s[tid][1]+ep_s[tid][2]+ep_s[tid][3]; }
        __syncthreads();
    }
    // ---- softmax over esr[300]
    float m=-3.4e38f;
    for (int t=tid;t<NT;t+=256) m=fmaxf(m,esr[t]);
    red[tid]=m; __syncthreads();
    for (int r=128;r>0;r>>=1){ if(tid<r) red[tid]=fmaxf(red[tid],red[tid+r]); __syncthreads(); }
    m=red[0]; __syncthreads();
    float ss=0.f;
    for (int t=tid;t<NT;t+=256) ss+=expf(SCL*(esr[t]-m));
    red[tid]=ss; __syncthreads();
    for (int r=128;r>0;r>>=1){ if(tid<r) red[tid]+=red[tid+r]; __syncthreads(); }
    const float inv = 1.f/red[0];
    for (int t=tid;t<NT;t+=256){
        const float w = expf(SCL*(esr[t]-m))*inv;
        wsm[t]=w;
        if (q==0){ wout[b*NT+t]=w; out_ws[((size_t)b*NTD+step)*NT+t]=w; }
    }
    __syncthreads();
    // ---- ctx for this block's d-quarter
    const int d = q*256 + tid;
    const float* ep2 = enc_pad + (size_t)b*NT*NE + d;
    float acc=0.f;
    #pragma unroll 4
    for (int t=0;t<NT;++t) acc += wsm[t]*ep2[(size_t)t*NE];
    ctx[b*NE + d] = acc;
}

// ---------------------------------------------------------------------------
// cvec (full K, no partials): cv[b][o] = ctx[b] . W_o[o] + b_o[o].
// grid 16 blocks, 256 thr, thread 2b x 2n.
// ---------------------------------------------------------------------------
__global__ __launch_bounds__(256) void k_cvec(const float* __restrict__ ctx,
    const float* __restrict__ W_o, const float* __restrict__ b_o,
    float* __restrict__ cv)
{
    const int tid=threadIdx.x;
    const int lane=tid&63, wv=tid>>6, bs=lane&15, nsl=lane>>4;
    const int n0 = blockIdx.x*32 + wv*8 + nsl*2;
    const float* x0 = ctx + bs*NE;
    const float* x1 = ctx + (bs+16)*NE;
    const float* w0 = W_o + (size_t)n0*NE;
    const float* w1 = w0 + NE;
    float a00=0.f,a01=0.f,a10=0.f,a11=0.f;
    #pragma unroll 8
    for (int c=0;c<256;++c){
        const int k = c*4;
        const float4 xa = *(const float4*)(x0+k);
        const float4 xb = *(const float4*)(x1+k);
        const float4 wa = *(const float4*)(w0+k);
        const float4 wb = *(const float4*)(w1+k);
        a00 += xa.x*wa.x+xa.y*wa.y+xa.z*wa.z+xa.w*wa.w;
        a01 += xa.x*wb.x+xa.y*wb.y+xa.z*wb.z+xa.w*wb.w;
        a10 += xb.x*wa.x+xb.y*wa.y+xb.z*wa.z+xb.w*wa.w;
        a11 += xb.x*wb.x+xb.y*wb.y+xb.z*wb.z+xb.w*wb.w;
    }
    cv[bs*NAO + n0]        = a00 + b_o[n0];
    cv[bs*NAO + n0+1]      = a01 + b_o[n0+1];
    cv[(bs+16)*NAO + n0]   = a10 + b_o[n0];
    cv[(bs+16)*NAO + n0+1] = a11 + b_o[n0+1];
}

// ---------------------------------------------------------------------------
// logits (full K): lp[b][v] = y[b] . W_out[v],  y = [dec_z | cvec].
// grid 313 blocks, 256 thr.
// ---------------------------------------------------------------------------
__global__ __launch_bounds__(256) void k_logits(const float* __restrict__ zbuf,
    const float* __restrict__ cv, const float* __restrict__ W_out,
    float* __restrict__ lp)
{
    __shared__ float xt[32][68];
    const int tid=threadIdx.x;
    const int lane=tid&63, wv=tid>>6, bs=lane&15, nsl=lane>>4;
    const int n0 = blockIdx.x*32 + wv*8 + nsl*2;
    const int rn0 = (n0   < NV)? n0   : NV-1;
    const int rn1 = (n0+1 < NV)? n0+1 : NV-1;
    const float* w0 = W_out + (size_t)rn0*1024;
    const float* w1 = W_out + (size_t)rn1*1024;
    const int sb = tid>>3, sk = (tid&7)*8;
    float a00=0.f,a01=0.f,a10=0.f,a11=0.f;
    for (int tile=0; tile<16; ++tile) {
        const int k0 = tile*64;
        const int gk = k0 + sk;
        float4 v0, v1;
        if (gk < 512) {
            const float4* p = (const float4*)(zbuf + sb*NH + gk);
            v0 = p[0]; v1 = p[1];
        } else {
            const float4* p = (const float4*)(cv + sb*NAO + (gk-512));
            v0 = p[0]; v1 = p[1];
        }
        __syncthreads();
        *(float4*)&xt[sb][sk]   = v0;
        *(float4*)&xt[sb][sk+4] = v1;
        __syncthreads();
        #pragma unroll
        for (int c=0;c<16;++c){
            const float4 xa = *(const float4*)&xt[bs][c*4];
            const float4 xb = *(const float4*)&xt[bs+16][c*4];
            const float4 wa = *(const float4*)(w0 + k0 + c*4);
            const float4 wb = *(const float4*)(w1 + k0 + c*4);
            a00 += xa.x*wa.x+xa.y*wa.y+xa.z*wa.z+xa.w*wa.w;
            a01 += xa.x*wb.x+xa.y*wb.y+xa.z*wb.z+xa.w*wb.w;
            a10 += xb.x*wa.x+xb.y*wa.y+xb.z*wa.z+xb.w*wa.w;
            a11 += xb.x*wb.x+xb.y*wb.y+xb.z*wb.z+xb.w*wb.w;
        }
    }
    if (n0 < NV){
        lp[(size_t)bs*NV + n0]      = a00;
        lp[(size_t)(bs+16)*NV + n0] = a10;
    }
    if (n0+1 < NV){
        lp[(size_t)bs*NV + n0+1]      = a01;
        lp[(size_t)(bs+16)*NV + n0+1] = a11;
    }
}

// ---------------------------------------------------------------------------
// finalize: logits = lp+b_out -> d_out; argmax (first-idx) + logsumexp
// ---------------------------------------------------------------------------
__global__ __launch_bounds__(256) void k_fin(const float* __restrict__ lp,
    const float* __restrict__ b_out, int step, float* __restrict__ out_logits,
    int* __restrict__ prev, float* __restrict__ out_preds, float* __restrict__ out_ylp)
{
    __shared__ float rv[256];
    __shared__ int   ri[256];
    const int b=blockIdx.x, tid=threadIdx.x;
    const float* p0 = lp + (size_t)b*NV;
    float* dst = out_logits + ((size_t)b*NTD + step)*NV;
    float m=-3.4e38f; int mi=NV;
    for (int v=tid; v<NV; v+=256){
        const float l = p0[v]+b_out[v];
        dst[v]=l;
        if (l>m){ m=l; mi=v; }
    }
    rv[tid]=m; ri[tid]=mi; __syncthreads();
    for (int s=128;s>0;s>>=1){
        if (tid<s){
            if (rv[tid+s]>rv[tid] || (rv[tid+s]==rv[tid] && ri[tid+s]<ri[tid])){
                rv[tid]=rv[tid+s]; ri[tid]=ri[tid+s];
            }
        }
        __syncthreads();
    }
    m=rv[0]; mi=ri[0]; __syncthreads();
    float ss=0.f;
    for (int v=tid; v<NV; v+=256) ss += expf(dst[v]-m);
    rv[tid]=ss; __syncthreads();
    for (int s=128;s>0;s>>=1){ if(tid<s) rv[tid]+=rv[tid+s]; __syncthreads(); }
    if (tid==0){
        prev[b]=mi;
        out_preds[b*NTD+step]=(float)mi;
        out_ylp[b*NTD+step]=-logf(rv[0]);
    }
}

// ---------------------------------------------------------------------------
extern "C" void kernel_launch(void* const* d_in, const int* in_sizes, int n_in,
                              void* d_out, int out_size, void* d_ws, size_t ws_size,
                              hipStream_t stream)
{
    const float* enc_pad   = (const float*)d_in[0];
    const int*   enc_len   = (const int*)d_in[1];
    const float* embedding = (const float*)d_in[2];
    const float* W_ih      = (const float*)d_in[3];
    const float* b_ih      = (const float*)d_in[4];
    const float* W_hh      = (const float*)d_in[5];
    const float* b_hh      = (const float*)d_in[6];
    const float* W_enc     = (const float*)d_in[7];
    const float* b_enc     = (const float*)d_in[8];
    const float* W_dec     = (const float*)d_in[9];
    const float* W_att     = (const float*)d_in[10];
    const float* conv_k    = (const float*)d_in[11];
    const float* W_g       = (const float*)d_in[12];
    const float* W_o       = (const float*)d_in[13];
    const float* b_o       = (const float*)d_in[14];
    const float* W_out     = (const float*)d_in[15];
    const float* b_out     = (const float*)d_in[16];

    float* out_logits = (float*)d_out;                        // [B,TD,V]
    float* out_ylp    = out_logits + (size_t)NB*NTD*NV;       // [B,TD]
    float* out_preds  = out_ylp + NB*NTD;                     // [B,TD]
    float* out_ws     = out_preds + NB*NTD;                   // [B,TD,T]

    float* f = (float*)d_ws;
    float* pre_enc = f;                                   // 9600*256
    float* zA      = pre_enc + (size_t)NB*NT*NA;          // 32*512
    float* zB      = zA + NB*NH;                          // 32*512
    float* dec_c   = zB + NB*NH;                          // 32*512
    float* cv      = dec_c + NB*NH;                       // 32*512
    float* wA      = cv + NB*NAO;                         // 32*300
    float* wB      = wA + NB*NT;                          // 32*300
    float* ctx     = wB + NB*NT;                          // 32*1024
    float* lp      = ctx + NB*NE;                         // 32*10000
    int*   prev    = (int*)(lp + (size_t)NB*NV);          // 32

    k_init<<<128, 256, 0, stream>>>(enc_len, zA, dec_c, cv, wA, prev);
    k_gemm_pre<<<dim3(NA/64, NB*NT/64), 256, 0, stream>>>(enc_pad, W_enc, b_enc, pre_enc, NA);

    for (int s = 0; s < NTD; ++s) {
        float* zin  = (s & 1) ? zB : zA;
        float* zout = (s & 1) ? zA : zB;
        float* win  = (s & 1) ? wB : wA;
        float* wout = (s & 1) ? wA : wB;
        k_gatelstm<<<64,  256, 0, stream>>>(embedding, prev, cv, zin,
                                            W_ih, b_ih, W_hh, b_hh, dec_c, zout);
        k_att     <<<128, 256, 0, stream>>>(pre_enc, win, conv_k, W_att, W_dec, W_g,
                                            zout, enc_pad, ctx, wout, out_ws, s);
        k_cvec    <<<16,  256, 0, stream>>>(ctx, W_o, b_o, cv);
        k_logits  <<<313, 256, 0, stream>>>(zout, cv, W_out, lp);
        k_fin     <<<32,  256, 0, stream>>>(lp, b_out, s, out_logits, prev,
                                            out_preds, out_ylp);
    }
}

// Round 4
// 11115.571 us; speedup vs baseline: 3.5054x; 2.6956x over previous
//
#include <hip/hip_runtime.h>
#include <math.h>

// Problem constants
#define NB   32      // batch
#define NT   300     // encoder frames
#define NE   1024    // encoder dim
#define NH   512     // hidden
#define NA   256     // attention dim
#define NC   10      // conv channels
#define NKW  201     // conv kernel width (2K+1), K=100
#define NV   10000   // vocab
#define NEMB 512     // embedding dim
#define NAO  512     // attention output dim
#define NTD  80      // decode steps
#define SCL  2.0f

__device__ __forceinline__ float sigf(float x){ return 1.f/(1.f+expf(-x)); }

// ---------------------------------------------------------------------------
// init: zbuf=0, dec_c(A)=0, cvp(2 parts)=0, prev=BOS, wbuf=w0(mask/len)
// ---------------------------------------------------------------------------
__global__ __launch_bounds__(256) void k_init(const int* __restrict__ enc_len,
    float* __restrict__ zbuf, float* __restrict__ cA, float* __restrict__ cvp,
    float* __restrict__ wbuf, int* __restrict__ prev)
{
    int i = blockIdx.x*256 + threadIdx.x;           // 32768 threads
    if (i < NB*NH)   { zbuf[i]=0.f; cA[i]=0.f; }
    if (i < 2*NB*NAO)  cvp[i]=0.f;
    if (i < NB*NT)   { int b=i/NT, t=i%NT; int len=enc_len[b];
                       wbuf[i] = (t<len)? 1.f/(float)len : 0.f; }
    if (i < NB)        prev[i]=1;                   // BOS
}

// ---------------------------------------------------------------------------
// Tiled GEMM: Cg[m][n] = A[m][:1024] . Wg[n][:1024] + bias[n].
// M=9600 rows, K=1024 exact.  Used for pre_enc (N=256) and ENC_O (N=512).
// ---------------------------------------------------------------------------
__global__ __launch_bounds__(256) void k_gemm_pre(const float* __restrict__ Ag,
    const float* __restrict__ Wg, const float* __restrict__ bias,
    float* __restrict__ Cg, int N)
{
    __shared__ float As[32][68];   // [kk][m]
    __shared__ float Bs[32][68];   // [kk][n]
    const int tid = threadIdx.x;
    const int m0 = blockIdx.y*64, n0 = blockIdx.x*64;
    const int r  = tid>>2, kg = (tid&3)*8;
    const int ty = tid>>4, tx = tid&15;
    float acc[4][4] = {};
    for (int k0 = 0; k0 < 1024; k0 += 32) {
        const float4 a0 = *(const float4*)(Ag + (size_t)(m0+r)*1024 + k0+kg);
        const float4 a1 = *(const float4*)(Ag + (size_t)(m0+r)*1024 + k0+kg+4);
        const float4 b0 = *(const float4*)(Wg + (size_t)(n0+r)*1024 + k0+kg);
        const float4 b1 = *(const float4*)(Wg + (size_t)(n0+r)*1024 + k0+kg+4);
        __syncthreads();
        As[kg+0][r]=a0.x; As[kg+1][r]=a0.y; As[kg+2][r]=a0.z; As[kg+3][r]=a0.w;
        As[kg+4][r]=a1.x; As[kg+5][r]=a1.y; As[kg+6][r]=a1.z; As[kg+7][r]=a1.w;
        Bs[kg+0][r]=b0.x; Bs[kg+1][r]=b0.y; Bs[kg+2][r]=b0.z; Bs[kg+3][r]=b0.w;
        Bs[kg+4][r]=b1.x; Bs[kg+5][r]=b1.y; Bs[kg+6][r]=b1.z; Bs[kg+7][r]=b1.w;
        __syncthreads();
        #pragma unroll
        for (int kk=0; kk<32; ++kk) {
            const float4 av = *(const float4*)&As[kk][ty*4];
            const float4 bv = *(const float4*)&Bs[kk][tx*4];
            const float a[4]={av.x,av.y,av.z,av.w};
            const float bb[4]={bv.x,bv.y,bv.z,bv.w};
            #pragma unroll
            for (int i=0;i<4;++i)
                #pragma unroll
                for (int j=0;j<4;++j) acc[i][j] += a[i]*bb[j];
        }
    }
    #pragma unroll
    for (int i=0;i<4;++i){
        const int m = m0 + ty*4 + i;
        #pragma unroll
        for (int j=0;j<4;++j)
            Cg[(size_t)m*N + n0 + tx*4 + j] = acc[i][j] + bias[n0+tx*4+j];
    }
}

// ---------------------------------------------------------------------------
// gates partials (R1-proven): gp[kp][b][n] = sum_{k chunk} x[b][k]*Wcat[n][k]
// x = [emb[prev] | cvec=cvp0+cvp1 | dec_z], grid (64,4), 256 thr.
// ---------------------------------------------------------------------------
__global__ __launch_bounds__(256) void k_gates(const float* __restrict__ emb,
    const int* __restrict__ prev, const float* __restrict__ cp,
    const float* __restrict__ zbuf, const float* __restrict__ W_ih,
    const float* __restrict__ W_hh, float* __restrict__ gp)
{
    __shared__ float xt[32][68];
    const int tid = threadIdx.x;
    const int kp  = blockIdx.y;                    // 0..3, chunks of 384
    const int lane = tid&63, wv = tid>>6;
    const int bs = lane&15, nsl = lane>>4;
    const int n0 = blockIdx.x*32 + wv*8 + nsl*2;
    const int sb = tid>>3, sk = (tid&7)*8;
    const int pvs = prev[sb];
    const float* wih0 = W_ih + (size_t)n0*1024;
    const float* whh0 = W_hh + (size_t)n0*512;
    float a00=0.f,a01=0.f,a10=0.f,a11=0.f;
    for (int tile=0; tile<6; ++tile) {
        const int k0 = kp*384 + tile*64;
        const int gk = k0 + sk;
        float4 v0, v1;
        if (gk < 512) {
            const float4* p = (const float4*)(emb + (size_t)pvs*NEMB + gk);
            v0 = p[0]; v1 = p[1];
        } else if (gk < 1024) {
            const float4* p0 = (const float4*)(cp + sb*NAO + (gk-512));
            const float4* p1 = (const float4*)(cp + NB*NAO + sb*NAO + (gk-512));
            const float4 x0=p0[0], x1=p1[0], y0=p0[1], y1=p1[1];
            v0 = make_float4(x0.x+x1.x, x0.y+x1.y, x0.z+x1.z, x0.w+x1.w);
            v1 = make_float4(y0.x+y1.x, y0.y+y1.y, y0.z+y1.z, y0.w+y1.w);
        } else {
            const float4* p = (const float4*)(zbuf + sb*NH + (gk-1024));
            v0 = p[0]; v1 = p[1];
        }
        __syncthreads();
        *(float4*)&xt[sb][sk]   = v0;
        *(float4*)&xt[sb][sk+4] = v1;
        __syncthreads();
        const float* w0 = (k0 < 1024) ? wih0 + k0        : whh0 + (k0-1024);
        const float* w1 = (k0 < 1024) ? wih0 + 1024 + k0 : whh0 + 512 + (k0-1024);
        #pragma unroll
        for (int c=0;c<16;++c){
            const float4 xa = *(const float4*)&xt[bs][c*4];
            const float4 xb = *(const float4*)&xt[bs+16][c*4];
            const float4 wa = *(const float4*)(w0 + c*4);
            const float4 wb = *(const float4*)(w1 + c*4);
            a00 += xa.x*wa.x+xa.y*wa.y+xa.z*wa.z+xa.w*wa.w;
            a01 += xa.x*wb.x+xa.y*wb.y+xa.z*wb.z+xa.w*wb.w;
            a10 += xb.x*wa.x+xb.y*wa.y+xb.z*wa.z+xb.w*wa.w;
            a11 += xb.x*wb.x+xb.y*wb.y+xb.z*wb.z+xb.w*wb.w;
        }
    }
    float* g = gp + (size_t)(kp*NB)*2048;
    g[(size_t)bs*2048 + n0]        = a00;
    g[(size_t)bs*2048 + n0+1]      = a01;
    g[(size_t)(bs+16)*2048 + n0]   = a10;
    g[(size_t)(bs+16)*2048 + n0+1] = a11;
}

// ---------------------------------------------------------------------------
// FUSED lstm + dec_t + conv + escore.  grid (5 t-chunks, 32 b), 256 thr.
// Each block redundantly computes the LSTM combine (cheap: 32 coalesced loads
// + activations per thread) and dec_t (2KB W_dec per thread) for its batch,
// then does conv+escore for its 60-t chunk (R1 k_escore shape).
// Chunk-0 block writes dec_c(out) and zbuf.  dec_c double-buffered.
// ---------------------------------------------------------------------------
__global__ __launch_bounds__(256) void k_attn(
    const float* __restrict__ gp, const float* __restrict__ b_ih,
    const float* __restrict__ b_hh, const float* __restrict__ cin,
    float* __restrict__ cout, float* __restrict__ zbuf,
    const float* __restrict__ W_dec, const float* __restrict__ pre_enc,
    const float* __restrict__ wbuf, const float* __restrict__ ck,
    const float* __restrict__ W_att, const float* __restrict__ W_g,
    float* __restrict__ ebuf)
{
    __shared__ float zs[NH];           // 512
    __shared__ float w_h[260];
    __shared__ float ck_s[NC*NKW];     // 2010
    __shared__ float wt_s[NA*NC];      // 2560
    __shared__ float dt_s[NA];
    __shared__ float wg_s[NA];
    __shared__ float cv_s[60*NC];      // 600
    __shared__ float ep_s[60][4];
    const int tid = threadIdx.x;
    const int b = blockIdx.y, t0 = blockIdx.x*60;
    // ---- LSTM combine (redundant per chunk; chunk 0 writes globals)
    for (int h = tid; h < NH; h += 256) {
        float g[4];
        #pragma unroll
        for (int r=0;r<4;++r){
            float s = b_ih[r*512+h] + b_hh[r*512+h];
            #pragma unroll
            for (int kp=0;kp<4;++kp) s += gp[(size_t)(kp*NB+b)*2048 + r*512 + h];
            g[r]=s;
        }
        const float c = sigf(g[1])*cin[b*NH+h] + sigf(g[0])*tanhf(g[2]);
        const float z = sigf(g[3])*tanhf(c);
        zs[h] = z;
        if (blockIdx.x==0){ cout[b*NH+h]=c; zbuf[b*NH+h]=z; }
    }
    // ---- constant/halo loads (independent of zs)
    for (int i=tid;i<260;i+=256){ const int gt=t0-100+i;
        w_h[i] = (gt>=0 && gt<NT)? wbuf[b*NT+gt] : 0.f; }
    for (int i=tid;i<NC*NKW;i+=256) ck_s[i]=ck[i];
    for (int i=tid;i<NA*NC;i+=256)  wt_s[i]=W_att[i];
    wg_s[tid] = W_g[tid];
    __syncthreads();
    // ---- dec_t: 32 groups of 8 lanes; group handles a = grp*8..+7
    {
        const int grp = tid>>3, l = tid&7;
        float4 zr[16];
        #pragma unroll
        for (int q=0;q<16;++q) zr[q] = *(const float4*)&zs[l*4 + q*32];
        #pragma unroll
        for (int j=0;j<8;++j){
            const int a = grp*8 + j;
            const float* w = W_dec + (size_t)a*NH;
            float sv = 0.f;
            #pragma unroll
            for (int q=0;q<16;++q){
                const float4 wv4 = *(const float4*)(w + l*4 + q*32);
                sv += zr[q].x*wv4.x + zr[q].y*wv4.y + zr[q].z*wv4.z + zr[q].w*wv4.w;
            }
            sv += __shfl_down(sv, 4, 8);
            sv += __shfl_down(sv, 2, 8);
            sv += __shfl_down(sv, 1, 8);
            if (l==0) dt_s[a] = sv;
        }
    }
    __syncthreads();
    // ---- conv for this 60-t chunk
    for (int i=tid;i<60*NC;i+=256){
        const int tl=i/NC, ch=i%NC;
        float s=0.f;
        const float* wp  = &w_h[tl];
        const float* ckp = &ck_s[ch*NKW];
        for (int k=0;k<NKW;++k) s += wp[k]*ckp[k];
        cv_s[i]=s;
    }
    __syncthreads();
    // ---- escore
    const int tq = tid&3, tl = tid>>2;
    if (tl < 60) {
        float cv[NC];
        #pragma unroll
        for (int ch=0;ch<NC;++ch) cv[ch]=cv_s[tl*NC+ch];
        const float* pe = pre_enc + (size_t)(b*NT + t0 + tl)*NA;
        float part=0.f;
        for (int i=0;i<64;++i){
            const int aa = tq + 4*i;
            float attc = 0.f;
            #pragma unroll
            for (int ch=0;ch<NC;++ch) attc += cv[ch]*wt_s[aa*NC+ch];
            part += tanhf(pe[aa] + dt_s[aa] + attc) * wg_s[aa];
        }
        ep_s[tl][tq] = part;
    }
    __syncthreads();
    if (tid < 60)
        ebuf[b*NT + t0 + tid] = ep_s[tid][0]+ep_s[tid][1]+ep_s[tid][2]+ep_s[tid][3];
}

// ---------------------------------------------------------------------------
// softmax (redundant x4 per batch) + cvec partials directly from ENC_O:
// cvp[th][b][o] = sum_{t in half th} w[b,t]*ENC_O[b,t,o]   (b_o folded in
// ENC_O; exact since sum_t w = 1).  grid 128 = (4 q = th*2+oc, 32 b).
// q==0 writes wbuf + out_ws.
// ---------------------------------------------------------------------------
__global__ __launch_bounds__(256) void k_ctxsm(const float* __restrict__ ebuf,
    const float* __restrict__ enc_o, float* __restrict__ cvp,
    float* __restrict__ wbuf, float* __restrict__ out_ws, int step)
{
    __shared__ float es[NT], wsm[NT], red[256];
    const int tid=threadIdx.x;
    const int b = blockIdx.x>>2, q = blockIdx.x&3;
    const int th = q>>1, oc = q&1;
    for (int t=tid;t<NT;t+=256) es[t]=ebuf[b*NT+t];
    __syncthreads();
    float m=-3.4e38f;
    for (int t=tid;t<NT;t+=256) m=fmaxf(m,es[t]);
    red[tid]=m; __syncthreads();
    for (int r=128;r>0;r>>=1){ if(tid<r) red[tid]=fmaxf(red[tid],red[tid+r]); __syncthreads(); }
    m=red[0]; __syncthreads();
    float ss=0.f;
    for (int t=tid;t<NT;t+=256) ss+=expf(SCL*(es[t]-m));
    red[tid]=ss; __syncthreads();
    for (int r=128;r>0;r>>=1){ if(tid<r) red[tid]+=red[tid+r]; __syncthreads(); }
    const float inv = 1.f/red[0];
    for (int t=tid;t<NT;t+=256){
        const float w = expf(SCL*(es[t]-m))*inv;
        wsm[t]=w;
        if (q==0){ wbuf[b*NT+t]=w; out_ws[((size_t)b*NTD+step)*NT+t]=w; }
    }
    __syncthreads();
    const int o = oc*256 + tid;
    const float* ep = enc_o + ((size_t)b*NT + th*150)*NAO + o;
    float acc=0.f;
    #pragma unroll 5
    for (int t=0;t<150;++t) acc += wsm[th*150+t]*ep[(size_t)t*NAO];
    cvp[(size_t)(th*NB+b)*NAO + o] = acc;
}

// ---------------------------------------------------------------------------
// logits partials (R1-proven): lp[kp][b][v] = sum_{k chunk} y[b][k]*W_out[v][k]
// y = [dec_z | cvec = cvp0+cvp1].  grid (313, 2), 256 thr.
// ---------------------------------------------------------------------------
__global__ __launch_bounds__(256) void k_logits(const float* __restrict__ zbuf,
    const float* __restrict__ cp, const float* __restrict__ W_out,
    float* __restrict__ lp)
{
    __shared__ float xt[32][68];
    const int tid=threadIdx.x, kp=blockIdx.y;
    const int lane=tid&63, wv=tid>>6, bs=lane&15, nsl=lane>>4;
    const int n0 = blockIdx.x*32 + wv*8 + nsl*2;
    const int rn0 = (n0   < NV)? n0   : NV-1;
    const int rn1 = (n0+1 < NV)? n0+1 : NV-1;
    const float* w0 = W_out + (size_t)rn0*1024;
    const float* w1 = W_out + (size_t)rn1*1024;
    const int sb = tid>>3, sk = (tid&7)*8;
    float a00=0.f,a01=0.f,a10=0.f,a11=0.f;
    for (int tile=0; tile<8; ++tile) {
        const int k0 = kp*512 + tile*64;
        const int gk = k0 + sk;
        float4 v0, v1;
        if (gk < 512) {
            const float4* p = (const float4*)(zbuf + sb*NH + gk);
            v0 = p[0]; v1 = p[1];
        } else {
            const float4* p0 = (const float4*)(cp + sb*NAO + (gk-512));
            const float4* p1 = (const float4*)(cp + NB*NAO + sb*NAO + (gk-512));
            const float4 x0=p0[0], x1=p1[0], y0=p0[1], y1=p1[1];
            v0 = make_float4(x0.x+x1.x, x0.y+x1.y, x0.z+x1.z, x0.w+x1.w);
            v1 = make_float4(y0.x+y1.x, y0.y+y1.y, y0.z+y1.z, y0.w+y1.w);
        }
        __syncthreads();
        *(float4*)&xt[sb][sk]   = v0;
        *(float4*)&xt[sb][sk+4] = v1;
        __syncthreads();
        #pragma unroll
        for (int c=0;c<16;++c){
            const float4 xa = *(const float4*)&xt[bs][c*4];
            const float4 xb = *(const float4*)&xt[bs+16][c*4];
            const float4 wa = *(const float4*)(w0 + k0 + c*4);
            const float4 wb = *(const float4*)(w1 + k0 + c*4);
            a00 += xa.x*wa.x+xa.y*wa.y+xa.z*wa.z+xa.w*wa.w;
            a01 += xa.x*wb.x+xa.y*wb.y+xa.z*wb.z+xa.w*wb.w;
            a10 += xb.x*wa.x+xb.y*wa.y+xb.z*wa.z+xb.w*wa.w;
            a11 += xb.x*wb.x+xb.y*wb.y+xb.z*wb.z+xb.w*wb.w;
        }
    }
    if (n0 < NV){
        lp[(size_t)(kp*NB+bs)*NV + n0]    = a00;
        lp[(size_t)(kp*NB+bs+16)*NV + n0] = a10;
    }
    if (n0+1 < NV){
        lp[(size_t)(kp*NB+bs)*NV + n0+1]    = a01;
        lp[(size_t)(kp*NB+bs+16)*NV + n0+1] = a11;
    }
}

// ---------------------------------------------------------------------------
// finalize (R1-proven): logits = lp0+lp1+b_out -> d_out; argmax + logsumexp
// ---------------------------------------------------------------------------
__global__ __launch_bounds__(256) void k_fin(const float* __restrict__ lp,
    const float* __restrict__ b_out, int step, float* __restrict__ out_logits,
    int* __restrict__ prev, float* __restrict__ out_preds, float* __restrict__ out_ylp)
{
    __shared__ float rv[256];
    __shared__ int   ri[256];
    const int b=blockIdx.x, tid=threadIdx.x;
    const float* p0 = lp + (size_t)b*NV;
    const float* p1 = lp + (size_t)(NB+b)*NV;
    float* dst = out_logits + ((size_t)b*NTD + step)*NV;
    float m=-3.4e38f; int mi=NV;
    for (int v=tid; v<NV; v+=256){
        const float l = p0[v]+p1[v]+b_out[v];
        dst[v]=l;
        if (l>m){ m=l; mi=v; }
    }
    rv[tid]=m; ri[tid]=mi; __syncthreads();
    for (int s=128;s>0;s>>=1){
        if (tid<s){
            if (rv[tid+s]>rv[tid] || (rv[tid+s]==rv[tid] && ri[tid+s]<ri[tid])){
                rv[tid]=rv[tid+s]; ri[tid]=ri[tid+s];
            }
        }
        __syncthreads();
    }
    m=rv[0]; mi=ri[0]; __syncthreads();
    float ss=0.f;
    for (int v=tid; v<NV; v+=256) ss += expf(dst[v]-m);
    rv[tid]=ss; __syncthreads();
    for (int s=128;s>0;s>>=1){ if(tid<s) rv[tid]+=rv[tid+s]; __syncthreads(); }
    if (tid==0){
        prev[b]=mi;
        out_preds[b*NTD+step]=(float)mi;
        out_ylp[b*NTD+step]=-logf(rv[0]);
    }
}

// ---------------------------------------------------------------------------
extern "C" void kernel_launch(void* const* d_in, const int* in_sizes, int n_in,
                              void* d_out, int out_size, void* d_ws, size_t ws_size,
                              hipStream_t stream)
{
    const float* enc_pad   = (const float*)d_in[0];
    const int*   enc_len   = (const int*)d_in[1];
    const float* embedding = (const float*)d_in[2];
    const float* W_ih      = (const float*)d_in[3];
    const float* b_ih      = (const float*)d_in[4];
    const float* W_hh      = (const float*)d_in[5];
    const float* b_hh      = (const float*)d_in[6];
    const float* W_enc     = (const float*)d_in[7];
    const float* b_enc     = (const float*)d_in[8];
    const float* W_dec     = (const float*)d_in[9];
    const float* W_att     = (const float*)d_in[10];
    const float* conv_k    = (const float*)d_in[11];
    const float* W_g       = (const float*)d_in[12];
    const float* W_o       = (const float*)d_in[13];
    const float* b_o       = (const float*)d_in[14];
    const float* W_out     = (const float*)d_in[15];
    const float* b_out     = (const float*)d_in[16];

    float* out_logits = (float*)d_out;                        // [B,TD,V]
    float* out_ylp    = out_logits + (size_t)NB*NTD*NV;       // [B,TD]
    float* out_preds  = out_ylp + NB*NTD;                     // [B,TD]
    float* out_ws     = out_preds + NB*NTD;                   // [B,TD,T]

    float* f = (float*)d_ws;
    float* pre_enc = f;                                   // 9600*256
    float* enc_o   = pre_enc + (size_t)NB*NT*NA;          // 9600*512
    float* zbuf    = enc_o + (size_t)NB*NT*NAO;           // 32*512
    float* cA      = zbuf + NB*NH;                        // 32*512
    float* cB      = cA + NB*NH;                          // 32*512
    float* gp      = cB + NB*NH;                          // 4*32*2048
    float* cvp     = gp + 4*NB*2048;                      // 2*32*512
    float* ebuf    = cvp + 2*NB*NAO;                      // 32*300
    float* wbuf    = ebuf + NB*NT;                        // 32*300
    float* lp      = wbuf + NB*NT;                        // 2*32*10000
    int*   prev    = (int*)(lp + (size_t)2*NB*NV);        // 32

    k_init<<<128, 256, 0, stream>>>(enc_len, zbuf, cA, cvp, wbuf, prev);
    k_gemm_pre<<<dim3(NA/64,  NB*NT/64), 256, 0, stream>>>(enc_pad, W_enc, b_enc, pre_enc, NA);
    k_gemm_pre<<<dim3(NAO/64, NB*NT/64), 256, 0, stream>>>(enc_pad, W_o,   b_o,   enc_o,   NAO);

    for (int s = 0; s < NTD; ++s) {
        float* cin  = (s & 1) ? cB : cA;
        float* cout = (s & 1) ? cA : cB;
        k_gates <<<dim3(64,4),  256, 0, stream>>>(embedding, prev, cvp, zbuf, W_ih, W_hh, gp);
        k_attn  <<<dim3(5,32),  256, 0, stream>>>(gp, b_ih, b_hh, cin, cout, zbuf,
                                                  W_dec, pre_enc, wbuf, conv_k, W_att, W_g, ebuf);
        k_ctxsm <<<128,         256, 0, stream>>>(ebuf, enc_o, cvp, wbuf, out_ws, s);
        k_logits<<<dim3(313,2), 256, 0, stream>>>(zbuf, cvp, W_out, lp);
        k_fin   <<<32,          256, 0, stream>>>(lp, b_out, s, out_logits, prev,
                                                  out_preds, out_ylp);
    }
}

// Round 5
// 10539.149 us; speedup vs baseline: 3.6971x; 1.0547x over previous
//
#include <hip/hip_runtime.h>
#include <math.h>

// Problem constants
#define NB   32      // batch
#define NT   300     // encoder frames
#define NE   1024    // encoder dim
#define NH   512     // hidden
#define NA   256     // attention dim
#define NC   10      // conv channels
#define NKW  201     // conv kernel width (2K+1), K=100
#define NV   10000   // vocab
#define NEMB 512     // embedding dim
#define NAO  512     // attention output dim
#define NTD  80      // decode steps
#define SCL  2.0f

__device__ __forceinline__ float sigf(float x){ return 1.f/(1.f+expf(-x)); }

// ---------------------------------------------------------------------------
// init: zbuf=0, dec_c(A)=0, cvp(4 parts)=0, prev=BOS, wbuf=w0(mask/len)
// ---------------------------------------------------------------------------
__global__ __launch_bounds__(256) void k_init(const int* __restrict__ enc_len,
    float* __restrict__ zbuf, float* __restrict__ cA, float* __restrict__ cvp,
    float* __restrict__ wbuf, int* __restrict__ prev)
{
    int i = blockIdx.x*256 + threadIdx.x;           // 65536 threads
    if (i < NB*NH)   { zbuf[i]=0.f; cA[i]=0.f; }
    if (i < 4*NB*NAO)  cvp[i]=0.f;
    if (i < NB*NT)   { int b=i/NT, t=i%NT; int len=enc_len[b];
                       wbuf[i] = (t<len)? 1.f/(float)len : 0.f; }
    if (i < NB)        prev[i]=1;                   // BOS
}

// ---------------------------------------------------------------------------
// Tiled GEMM: Cg[m][n] = A[m][:1024] . Wg[n][:1024] + bias[n].
// M=9600 rows, K=1024 exact.  Used for pre_enc (N=256) and ENC_O (N=512).
// ---------------------------------------------------------------------------
__global__ __launch_bounds__(256) void k_gemm_pre(const float* __restrict__ Ag,
    const float* __restrict__ Wg, const float* __restrict__ bias,
    float* __restrict__ Cg, int N)
{
    __shared__ float As[32][68];   // [kk][m]
    __shared__ float Bs[32][68];   // [kk][n]
    const int tid = threadIdx.x;
    const int m0 = blockIdx.y*64, n0 = blockIdx.x*64;
    const int r  = tid>>2, kg = (tid&3)*8;
    const int ty = tid>>4, tx = tid&15;
    float acc[4][4] = {};
    for (int k0 = 0; k0 < 1024; k0 += 32) {
        const float4 a0 = *(const float4*)(Ag + (size_t)(m0+r)*1024 + k0+kg);
        const float4 a1 = *(const float4*)(Ag + (size_t)(m0+r)*1024 + k0+kg+4);
        const float4 b0 = *(const float4*)(Wg + (size_t)(n0+r)*1024 + k0+kg);
        const float4 b1 = *(const float4*)(Wg + (size_t)(n0+r)*1024 + k0+kg+4);
        __syncthreads();
        As[kg+0][r]=a0.x; As[kg+1][r]=a0.y; As[kg+2][r]=a0.z; As[kg+3][r]=a0.w;
        As[kg+4][r]=a1.x; As[kg+5][r]=a1.y; As[kg+6][r]=a1.z; As[kg+7][r]=a1.w;
        Bs[kg+0][r]=b0.x; Bs[kg+1][r]=b0.y; Bs[kg+2][r]=b0.z; Bs[kg+3][r]=b0.w;
        Bs[kg+4][r]=b1.x; Bs[kg+5][r]=b1.y; Bs[kg+6][r]=b1.z; Bs[kg+7][r]=b1.w;
        __syncthreads();
        #pragma unroll
        for (int kk=0; kk<32; ++kk) {
            const float4 av = *(const float4*)&As[kk][ty*4];
            const float4 bv = *(const float4*)&Bs[kk][tx*4];
            const float a[4]={av.x,av.y,av.z,av.w};
            const float bb[4]={bv.x,bv.y,bv.z,bv.w};
            #pragma unroll
            for (int i=0;i<4;++i)
                #pragma unroll
                for (int j=0;j<4;++j) acc[i][j] += a[i]*bb[j];
        }
    }
    #pragma unroll
    for (int i=0;i<4;++i){
        const int m = m0 + ty*4 + i;
        #pragma unroll
        for (int j=0;j<4;++j)
            Cg[(size_t)m*N + n0 + tx*4 + j] = acc[i][j] + bias[n0+tx*4+j];
    }
}

// ---------------------------------------------------------------------------
// gates partials: gp[kp][b][n] = sum_{k chunk} x[b][k]*Wcat[n][k]
// x = [emb[prev] | cvec=sum cvp0..3 | dec_z], grid (64,4), 256 thr.
// ---------------------------------------------------------------------------
__global__ __launch_bounds__(256) void k_gates(const float* __restrict__ emb,
    const int* __restrict__ prev, const float* __restrict__ cp,
    const float* __restrict__ zbuf, const float* __restrict__ W_ih,
    const float* __restrict__ W_hh, float* __restrict__ gp)
{
    __shared__ float xt[32][68];
    const int tid = threadIdx.x;
    const int kp  = blockIdx.y;                    // 0..3, chunks of 384
    const int lane = tid&63, wv = tid>>6;
    const int bs = lane&15, nsl = lane>>4;
    const int n0 = blockIdx.x*32 + wv*8 + nsl*2;
    const int sb = tid>>3, sk = (tid&7)*8;
    const int pvs = prev[sb];
    const float* wih0 = W_ih + (size_t)n0*1024;
    const float* whh0 = W_hh + (size_t)n0*512;
    float a00=0.f,a01=0.f,a10=0.f,a11=0.f;
    for (int tile=0; tile<6; ++tile) {
        const int k0 = kp*384 + tile*64;
        const int gk = k0 + sk;
        float4 v0, v1;
        if (gk < 512) {
            const float4* p = (const float4*)(emb + (size_t)pvs*NEMB + gk);
            v0 = p[0]; v1 = p[1];
        } else if (gk < 1024) {
            const int off = gk-512;
            const float4* p0 = (const float4*)(cp + sb*NAO + off);
            const float4* p1 = (const float4*)(cp + NB*NAO + sb*NAO + off);
            const float4* p2 = (const float4*)(cp + 2*NB*NAO + sb*NAO + off);
            const float4* p3 = (const float4*)(cp + 3*NB*NAO + sb*NAO + off);
            const float4 a0=p0[0], a1=p1[0], a2=p2[0], a3=p3[0];
            const float4 b0=p0[1], b1=p1[1], b2=p2[1], b3=p3[1];
            v0 = make_float4(a0.x+a1.x+a2.x+a3.x, a0.y+a1.y+a2.y+a3.y,
                             a0.z+a1.z+a2.z+a3.z, a0.w+a1.w+a2.w+a3.w);
            v1 = make_float4(b0.x+b1.x+b2.x+b3.x, b0.y+b1.y+b2.y+b3.y,
                             b0.z+b1.z+b2.z+b3.z, b0.w+b1.w+b2.w+b3.w);
        } else {
            const float4* p = (const float4*)(zbuf + sb*NH + (gk-1024));
            v0 = p[0]; v1 = p[1];
        }
        __syncthreads();
        *(float4*)&xt[sb][sk]   = v0;
        *(float4*)&xt[sb][sk+4] = v1;
        __syncthreads();
        const float* w0 = (k0 < 1024) ? wih0 + k0        : whh0 + (k0-1024);
        const float* w1 = (k0 < 1024) ? wih0 + 1024 + k0 : whh0 + 512 + (k0-1024);
        #pragma unroll
        for (int c=0;c<16;++c){
            const float4 xa = *(const float4*)&xt[bs][c*4];
            const float4 xb = *(const float4*)&xt[bs+16][c*4];
            const float4 wa = *(const float4*)(w0 + c*4);
            const float4 wb = *(const float4*)(w1 + c*4);
            a00 += xa.x*wa.x+xa.y*wa.y+xa.z*wa.z+xa.w*wa.w;
            a01 += xa.x*wb.x+xa.y*wb.y+xa.z*wb.z+xa.w*wb.w;
            a10 += xb.x*wa.x+xb.y*wa.y+xb.z*wa.z+xb.w*wa.w;
            a11 += xb.x*wb.x+xb.y*wb.y+xb.z*wb.z+xb.w*wb.w;
        }
    }
    float* g = gp + (size_t)(kp*NB)*2048;
    g[(size_t)bs*2048 + n0]        = a00;
    g[(size_t)bs*2048 + n0+1]      = a01;
    g[(size_t)(bs+16)*2048 + n0]   = a10;
    g[(size_t)(bs+16)*2048 + n0+1] = a11;
}

// ---------------------------------------------------------------------------
// FUSED lstm + dec_t + conv + escore.  grid (5 t-chunks, 32 b), 256 thr.
// Chunk-0 block writes dec_c(out) and zbuf.  dec_c double-buffered.
// ---------------------------------------------------------------------------
__global__ __launch_bounds__(256) void k_attn(
    const float* __restrict__ gp, const float* __restrict__ b_ih,
    const float* __restrict__ b_hh, const float* __restrict__ cin,
    float* __restrict__ cout, float* __restrict__ zbuf,
    const float* __restrict__ W_dec, const float* __restrict__ pre_enc,
    const float* __restrict__ wbuf, const float* __restrict__ ck,
    const float* __restrict__ W_att, const float* __restrict__ W_g,
    float* __restrict__ ebuf)
{
    __shared__ float zs[NH];           // 512
    __shared__ float w_h[260];
    __shared__ float ck_s[NC*NKW];     // 2010
    __shared__ float wt_s[NA*NC];      // 2560
    __shared__ float dt_s[NA];
    __shared__ float wg_s[NA];
    __shared__ float cv_s[60*NC];      // 600
    __shared__ float ep_s[60][4];
    const int tid = threadIdx.x;
    const int b = blockIdx.y, t0 = blockIdx.x*60;
    // ---- LSTM combine (redundant per chunk; chunk 0 writes globals)
    for (int h = tid; h < NH; h += 256) {
        float g[4];
        #pragma unroll
        for (int r=0;r<4;++r){
            float s = b_ih[r*512+h] + b_hh[r*512+h];
            #pragma unroll
            for (int kp=0;kp<4;++kp) s += gp[(size_t)(kp*NB+b)*2048 + r*512 + h];
            g[r]=s;
        }
        const float c = sigf(g[1])*cin[b*NH+h] + sigf(g[0])*tanhf(g[2]);
        const float z = sigf(g[3])*tanhf(c);
        zs[h] = z;
        if (blockIdx.x==0){ cout[b*NH+h]=c; zbuf[b*NH+h]=z; }
    }
    // ---- constant/halo loads (independent of zs)
    for (int i=tid;i<260;i+=256){ const int gt=t0-100+i;
        w_h[i] = (gt>=0 && gt<NT)? wbuf[b*NT+gt] : 0.f; }
    for (int i=tid;i<NC*NKW;i+=256) ck_s[i]=ck[i];
    for (int i=tid;i<NA*NC;i+=256)  wt_s[i]=W_att[i];
    wg_s[tid] = W_g[tid];
    __syncthreads();
    // ---- dec_t: 32 groups of 8 lanes; group handles a = grp*8..+7
    {
        const int grp = tid>>3, l = tid&7;
        float4 zr[16];
        #pragma unroll
        for (int q=0;q<16;++q) zr[q] = *(const float4*)&zs[l*4 + q*32];
        #pragma unroll
        for (int j=0;j<8;++j){
            const int a = grp*8 + j;
            const float* w = W_dec + (size_t)a*NH;
            float sv = 0.f;
            #pragma unroll
            for (int q=0;q<16;++q){
                const float4 wv4 = *(const float4*)(w + l*4 + q*32);
                sv += zr[q].x*wv4.x + zr[q].y*wv4.y + zr[q].z*wv4.z + zr[q].w*wv4.w;
            }
            sv += __shfl_down(sv, 4, 8);
            sv += __shfl_down(sv, 2, 8);
            sv += __shfl_down(sv, 1, 8);
            if (l==0) dt_s[a] = sv;
        }
    }
    __syncthreads();
    // ---- conv for this 60-t chunk
    for (int i=tid;i<60*NC;i+=256){
        const int tl=i/NC, ch=i%NC;
        float s=0.f;
        const float* wp  = &w_h[tl];
        const float* ckp = &ck_s[ch*NKW];
        for (int k=0;k<NKW;++k) s += wp[k]*ckp[k];
        cv_s[i]=s;
    }
    __syncthreads();
    // ---- escore
    const int tq = tid&3, tl = tid>>2;
    if (tl < 60) {
        float cv[NC];
        #pragma unroll
        for (int ch=0;ch<NC;++ch) cv[ch]=cv_s[tl*NC+ch];
        const float* pe = pre_enc + (size_t)(b*NT + t0 + tl)*NA;
        float part=0.f;
        for (int i=0;i<64;++i){
            const int aa = tq + 4*i;
            float attc = 0.f;
            #pragma unroll
            for (int ch=0;ch<NC;++ch) attc += cv[ch]*wt_s[aa*NC+ch];
            part += tanhf(pe[aa] + dt_s[aa] + attc) * wg_s[aa];
        }
        ep_s[tl][tq] = part;
    }
    __syncthreads();
    if (tid < 60)
        ebuf[b*NT + t0 + tid] = ep_s[tid][0]+ep_s[tid][1]+ep_s[tid][2]+ep_s[tid][3];
}

// ---------------------------------------------------------------------------
// softmax (redundant x8 per batch) + cvec partials from ENC_O:
// cvp[th][b][o] = sum_{t in quarter th} w[b,t]*ENC_O[b,t,o]   (b_o folded;
// exact since sum_t w = 1).  grid 256 = (32 b x 8 q), q = th*2+oc.
// q==0 writes wbuf + out_ws.
// ---------------------------------------------------------------------------
__global__ __launch_bounds__(256) void k_ctxsm(const float* __restrict__ ebuf,
    const float* __restrict__ enc_o, float* __restrict__ cvp,
    float* __restrict__ wbuf, float* __restrict__ out_ws, int step)
{
    __shared__ float es[NT], wsm[NT], red[256];
    const int tid=threadIdx.x;
    const int b = blockIdx.x>>3, q = blockIdx.x&7;
    const int th = q>>1, oc = q&1;
    for (int t=tid;t<NT;t+=256) es[t]=ebuf[b*NT+t];
    __syncthreads();
    float m=-3.4e38f;
    for (int t=tid;t<NT;t+=256) m=fmaxf(m,es[t]);
    red[tid]=m; __syncthreads();
    for (int r=128;r>0;r>>=1){ if(tid<r) red[tid]=fmaxf(red[tid],red[tid+r]); __syncthreads(); }
    m=red[0]; __syncthreads();
    float ss=0.f;
    for (int t=tid;t<NT;t+=256) ss+=expf(SCL*(es[t]-m));
    red[tid]=ss; __syncthreads();
    for (int r=128;r>0;r>>=1){ if(tid<r) red[tid]+=red[tid+r]; __syncthreads(); }
    const float inv = 1.f/red[0];
    for (int t=tid;t<NT;t+=256){
        const float w = expf(SCL*(es[t]-m))*inv;
        wsm[t]=w;
        if (q==0){ wbuf[b*NT+t]=w; out_ws[((size_t)b*NTD+step)*NT+t]=w; }
    }
    __syncthreads();
    const int o = oc*256 + tid;
    const float* ep = enc_o + ((size_t)b*NT + th*75)*NAO + o;
    float acc=0.f;
    #pragma unroll
    for (int t=0;t<75;++t) acc += wsm[th*75+t]*ep[(size_t)t*NAO];
    cvp[(size_t)(th*NB+b)*NAO + o] = acc;
}

// ---------------------------------------------------------------------------
// logits partials: lp[kp][b][v] = sum_{k in 256-chunk} y[b][k]*W_out[v][k]
// y = [dec_z (512) | cvec = cvp0+..+cvp3 (512)].  grid (313, 4), 256 thr.
// ---------------------------------------------------------------------------
__global__ __launch_bounds__(256) void k_logits(const float* __restrict__ zbuf,
    const float* __restrict__ cp, const float* __restrict__ W_out,
    float* __restrict__ lp)
{
    __shared__ float xt[32][68];
    const int tid=threadIdx.x, kp=blockIdx.y;
    const int lane=tid&63, wv=tid>>6, bs=lane&15, nsl=lane>>4;
    const int n0 = blockIdx.x*32 + wv*8 + nsl*2;
    const int rn0 = (n0   < NV)? n0   : NV-1;
    const int rn1 = (n0+1 < NV)? n0+1 : NV-1;
    const float* w0 = W_out + (size_t)rn0*1024;
    const float* w1 = W_out + (size_t)rn1*1024;
    const int sb = tid>>3, sk = (tid&7)*8;
    float a00=0.f,a01=0.f,a10=0.f,a11=0.f;
    for (int tile=0; tile<4; ++tile) {
        const int k0 = kp*256 + tile*64;
        const int gk = k0 + sk;
        float4 v0, v1;
        if (gk < 512) {
            const float4* p = (const float4*)(zbuf + sb*NH + gk);
            v0 = p[0]; v1 = p[1];
        } else {
            const int off = gk-512;
            const float4* p0 = (const float4*)(cp + sb*NAO + off);
            const float4* p1 = (const float4*)(cp + NB*NAO + sb*NAO + off);
            const float4* p2 = (const float4*)(cp + 2*NB*NAO + sb*NAO + off);
            const float4* p3 = (const float4*)(cp + 3*NB*NAO + sb*NAO + off);
            const float4 a0=p0[0], a1=p1[0], a2=p2[0], a3=p3[0];
            const float4 b0=p0[1], b1=p1[1], b2=p2[1], b3=p3[1];
            v0 = make_float4(a0.x+a1.x+a2.x+a3.x, a0.y+a1.y+a2.y+a3.y,
                             a0.z+a1.z+a2.z+a3.z, a0.w+a1.w+a2.w+a3.w);
            v1 = make_float4(b0.x+b1.x+b2.x+b3.x, b0.y+b1.y+b2.y+b3.y,
                             b0.z+b1.z+b2.z+b3.z, b0.w+b1.w+b2.w+b3.w);
        }
        __syncthreads();
        *(float4*)&xt[sb][sk]   = v0;
        *(float4*)&xt[sb][sk+4] = v1;
        __syncthreads();
        #pragma unroll
        for (int c=0;c<16;++c){
            const float4 xa = *(const float4*)&xt[bs][c*4];
            const float4 xb = *(const float4*)&xt[bs+16][c*4];
            const float4 wa = *(const float4*)(w0 + k0 + c*4);
            const float4 wb = *(const float4*)(w1 + k0 + c*4);
            a00 += xa.x*wa.x+xa.y*wa.y+xa.z*wa.z+xa.w*wa.w;
            a01 += xa.x*wb.x+xa.y*wb.y+xa.z*wb.z+xa.w*wb.w;
            a10 += xb.x*wa.x+xb.y*wa.y+xb.z*wa.z+xb.w*wa.w;
            a11 += xb.x*wb.x+xb.y*wb.y+xb.z*wb.z+xb.w*wb.w;
        }
    }
    if (n0 < NV){
        lp[(size_t)(kp*NB+bs)*NV + n0]    = a00;
        lp[(size_t)(kp*NB+bs+16)*NV + n0] = a10;
    }
    if (n0+1 < NV){
        lp[(size_t)(kp*NB+bs)*NV + n0+1]    = a01;
        lp[(size_t)(kp*NB+bs+16)*NV + n0+1] = a11;
    }
}

// ---------------------------------------------------------------------------
// finalize: logits = lp0+lp1+lp2+lp3+b_out -> d_out; argmax + logsumexp
// ---------------------------------------------------------------------------
__global__ __launch_bounds__(256) void k_fin(const float* __restrict__ lp,
    const float* __restrict__ b_out, int step, float* __restrict__ out_logits,
    int* __restrict__ prev, float* __restrict__ out_preds, float* __restrict__ out_ylp)
{
    __shared__ float rv[256];
    __shared__ int   ri[256];
    const int b=blockIdx.x, tid=threadIdx.x;
    const float* p0 = lp + (size_t)b*NV;
    const float* p1 = lp + (size_t)(NB+b)*NV;
    const float* p2 = lp + (size_t)(2*NB+b)*NV;
    const float* p3 = lp + (size_t)(3*NB+b)*NV;
    float* dst = out_logits + ((size_t)b*NTD + step)*NV;
    float m=-3.4e38f; int mi=NV;
    for (int v=tid; v<NV; v+=256){
        const float l = p0[v]+p1[v]+p2[v]+p3[v]+b_out[v];
        dst[v]=l;
        if (l>m){ m=l; mi=v; }
    }
    rv[tid]=m; ri[tid]=mi; __syncthreads();
    for (int s=128;s>0;s>>=1){
        if (tid<s){
            if (rv[tid+s]>rv[tid] || (rv[tid+s]==rv[tid] && ri[tid+s]<ri[tid])){
                rv[tid]=rv[tid+s]; ri[tid]=ri[tid+s];
            }
        }
        __syncthreads();
    }
    m=rv[0]; mi=ri[0]; __syncthreads();
    float ss=0.f;
    for (int v=tid; v<NV; v+=256) ss += expf(dst[v]-m);
    rv[tid]=ss; __syncthreads();
    for (int s=128;s>0;s>>=1){ if(tid<s) rv[tid]+=rv[tid+s]; __syncthreads(); }
    if (tid==0){
        prev[b]=mi;
        out_preds[b*NTD+step]=(float)mi;
        out_ylp[b*NTD+step]=-logf(rv[0]);
    }
}

// ---------------------------------------------------------------------------
extern "C" void kernel_launch(void* const* d_in, const int* in_sizes, int n_in,
                              void* d_out, int out_size, void* d_ws, size_t ws_size,
                              hipStream_t stream)
{
    const float* enc_pad   = (const float*)d_in[0];
    const int*   enc_len   = (const int*)d_in[1];
    const float* embedding = (const float*)d_in[2];
    const float* W_ih      = (const float*)d_in[3];
    const float* b_ih      = (const float*)d_in[4];
    const float* W_hh      = (const float*)d_in[5];
    const float* b_hh      = (const float*)d_in[6];
    const float* W_enc     = (const float*)d_in[7];
    const float* b_enc     = (const float*)d_in[8];
    const float* W_dec     = (const float*)d_in[9];
    const float* W_att     = (const float*)d_in[10];
    const float* conv_k    = (const float*)d_in[11];
    const float* W_g       = (const float*)d_in[12];
    const float* W_o       = (const float*)d_in[13];
    const float* b_o       = (const float*)d_in[14];
    const float* W_out     = (const float*)d_in[15];
    const float* b_out     = (const float*)d_in[16];

    float* out_logits = (float*)d_out;                        // [B,TD,V]
    float* out_ylp    = out_logits + (size_t)NB*NTD*NV;       // [B,TD]
    float* out_preds  = out_ylp + NB*NTD;                     // [B,TD]
    float* out_ws     = out_preds + NB*NTD;                   // [B,TD,T]

    float* f = (float*)d_ws;
    float* pre_enc = f;                                   // 9600*256
    float* enc_o   = pre_enc + (size_t)NB*NT*NA;          // 9600*512
    float* zbuf    = enc_o + (size_t)NB*NT*NAO;           // 32*512
    float* cA      = zbuf + NB*NH;                        // 32*512
    float* cB      = cA + NB*NH;                          // 32*512
    float* gp      = cB + NB*NH;                          // 4*32*2048
    float* cvp     = gp + 4*NB*2048;                      // 4*32*512
    float* ebuf    = cvp + 4*NB*NAO;                      // 32*300
    float* wbuf    = ebuf + NB*NT;                        // 32*300
    float* lp      = wbuf + NB*NT;                        // 4*32*10000
    int*   prev    = (int*)(lp + (size_t)4*NB*NV);        // 32

    k_init<<<256, 256, 0, stream>>>(enc_len, zbuf, cA, cvp, wbuf, prev);
    k_gemm_pre<<<dim3(NA/64,  NB*NT/64), 256, 0, stream>>>(enc_pad, W_enc, b_enc, pre_enc, NA);
    k_gemm_pre<<<dim3(NAO/64, NB*NT/64), 256, 0, stream>>>(enc_pad, W_o,   b_o,   enc_o,   NAO);

    for (int s = 0; s < NTD; ++s) {
        float* cin  = (s & 1) ? cB : cA;
        float* cout = (s & 1) ? cA : cB;
        k_gates <<<dim3(64,4),  256, 0, stream>>>(embedding, prev, cvp, zbuf, W_ih, W_hh, gp);
        k_attn  <<<dim3(5,32),  256, 0, stream>>>(gp, b_ih, b_hh, cin, cout, zbuf,
                                                  W_dec, pre_enc, wbuf, conv_k, W_att, W_g, ebuf);
        k_ctxsm <<<256,         256, 0, stream>>>(ebuf, enc_o, cvp, wbuf, out_ws, s);
        k_logits<<<dim3(313,4), 256, 0, stream>>>(zbuf, cvp, W_out, lp);
        k_fin   <<<32,          256, 0, stream>>>(lp, b_out, s, out_logits, prev,
                                                  out_preds, out_ylp);
    }
}